// Round 12
// baseline (343.139 us; speedup 1.0000x reference)
//
#include <hip/hip_runtime.h>
#include <math.h>

#define N_NODES 50000
#define N_EDGES 800000
#define H 128
#define EIN 257
#define EPB 64    // edges per block (fallback kernel)
#define EPB2 128  // edges per block (main kernel)
#define NWG_EDGE (N_EDGES / EPB)     // 12500
#define NWG2 (N_EDGES / EPB2)        // 6250
#define CNT_PAD 50176                // 196*256
#define NBS 196                      // scan blocks

typedef short bf16x8 __attribute__((ext_vector_type(8)));
typedef short bf16x4 __attribute__((ext_vector_type(4)));
typedef short bf16x2 __attribute__((ext_vector_type(2)));
typedef float f32x4 __attribute__((ext_vector_type(4)));

static __device__ __forceinline__ short f2bf(float x) {
    unsigned u = __builtin_bit_cast(unsigned, x);
    unsigned r = (u + 0x7FFFu + ((u >> 16) & 1u)) >> 16;
    return (short)r;
}

static __device__ __forceinline__ short f2bfr(float x) {
    return (short)((__builtin_bit_cast(unsigned, x) + 0x8000u) >> 16);
}

static __device__ __forceinline__ float bf2f(short s) {
    return __builtin_bit_cast(float, ((unsigned)(unsigned short)s) << 16);
}

static __device__ __forceinline__ float silu(float x) {
#if __has_builtin(__builtin_amdgcn_rcpf)
    return x * __builtin_amdgcn_rcpf(1.0f + __expf(-x));
#else
    return x / (1.0f + __expf(-x));
#endif
}

static __device__ __forceinline__ void pk_agg_add(unsigned* addr, unsigned val) {
#if __has_builtin(__builtin_amdgcn_global_atomic_fadd_v2bf16)
    bf16x2 v = __builtin_bit_cast(bf16x2, val);
    (void)__builtin_amdgcn_global_atomic_fadd_v2bf16(
        (__attribute__((address_space(1))) bf16x2*)(unsigned long long)addr, v);
#else
    asm volatile("global_atomic_pk_add_bf16 %0, %1, off"
                 :: "v"(addr), "v"(val) : "memory");
#endif
}

#define P_W1  (128*264)
#define P_W2  (128*128)
#define P_TOT (2*(P_W1 + P_W2))
#define NH4   (N_NODES * H / 4)
#define AGG16 (N_NODES * H * 2 / 16)
#define POS4  ((N_NODES * 3 + 3) / 4)
#define NW3   (128*128)
#define PROJ_NB ((N_NODES + 63) / 64)    // 782
#define TSTR  172   // s_t row stride (shorts): stride 86 dwords -> ~2-way reads

// NT-hint policy (R8+R10 lessons): NO nontemporal loads/stores anywhere.
// NT on gathers with L2 reuse drops hit rate (+18us); NT on dense-but-random
// 8B stores defeats L2 write-combining (+8us). Plain accesses win everywhere.

// ---- prep_w: weight conversions, W3 = Wc1@We2, bc1p, Wfold (inline into
// Wn1b cols 128..255 when fold), bfold = Wn1[:,128:]@be2, cnt8 zero ----
__global__ __launch_bounds__(256) void prep_w(
    const float* __restrict__ We1, const float* __restrict__ We2,
    const float* __restrict__ Wc1, const float* __restrict__ be2,
    const float* __restrict__ bc1,
    const float* __restrict__ Wn1, const float* __restrict__ Wn2,
    short* __restrict__ W1b, short* __restrict__ W2b, short* __restrict__ W3b,
    short* __restrict__ Wn1b, short* __restrict__ Wn2b,
    float* __restrict__ w256f, float* __restrict__ bc1p,
    float* __restrict__ bfold,
    unsigned* __restrict__ cnt, int cntn, int fold)
{
    int i = blockIdx.x * 256 + threadIdx.x;
    if (i < P_TOT) {
        if (i < P_W1) {
            int j = i / 264, k = i % 264;
            W1b[i] = (k < EIN) ? f2bf(We1[j * EIN + k]) : (short)0;
        } else if (i < P_W1 + P_W2) {
            int t = i - P_W1;
            W2b[t] = f2bf(We2[t]);
        } else if (i < 2 * P_W1 + P_W2) {
            int t = i - P_W1 - P_W2;
            int j = t / 264, k = t % 264;
            short v;
            if (k < 128) v = f2bf(Wn1[j * 256 + k]);
            else if (k < 256) {
                if (fold) {           // Wfold = Wn1[:,128:] @ We2
                    const float* wr = &Wn1[j * 256 + 128];
                    const float* wc = &We2[k - 128];
                    float acc = 0.f;
                    #pragma unroll 8
                    for (int o = 0; o < 128; ++o) acc += wr[o] * wc[o * 128];
                    v = f2bf(acc);
                } else v = f2bf(Wn1[j * 256 + k]);
            } else v = 0;
            Wn1b[t] = v;
        } else {
            int t = i - 2 * P_W1 - P_W2;
            Wn2b[t] = f2bf(Wn2[t]);
        }
        return;
    }
    i -= P_TOT;
    if (i < 128) { w256f[i] = We1[i * EIN + 256]; return; }
    i -= 128;
    if (i < NW3) {                       // W3 = Wc1 @ We2
        int j = i >> 7, k = i & 127;
        const float* wr = &Wc1[j * 128];
        float acc = 0.f;
        #pragma unroll 8
        for (int o = 0; o < 128; ++o)
            acc += wr[o] * We2[o * 128 + k];
        W3b[i] = f2bf(acc);
        return;
    }
    i -= NW3;
    if (i < 128) {                       // bc1p = bc1 + Wc1 @ be2
        const float* wr = &Wc1[i * 128];
        float acc = bc1[i];
        #pragma unroll 8
        for (int o = 0; o < 128; ++o) acc += wr[o] * be2[o];
        bc1p[i] = acc;
        return;
    }
    i -= 128;
    if (i < 128) {                       // bfold = Wn1[:,128:] @ be2
        const float* wr = &Wn1[i * 256 + 128];
        float acc = 0.f;
        #pragma unroll 8
        for (int o = 0; o < 128; ++o) acc += wr[o] * be2[o];
        bfold[i] = acc;
        return;
    }
    i -= 128;
    if (cnt && i < cntn) cnt[i] = 0u;
}

// ---- prep2: proj blocks + streaming rest in ONE dispatch.
// Histogram XCD-PRIVATIZED: bucket x = (edge>>8)&7 == physical XCD of the
// processing block (round-robin dispatch) -> atomics resolve in local L2. ----
template<bool PROJ_ON>
__global__ __launch_bounds__(256) void prep2(
    int proj_nb,
    const float* __restrict__ h, const short* __restrict__ W1b,
    const float* __restrict__ be1,
    short* __restrict__ Abf, short* __restrict__ Bbf,
    int nh4, short* __restrict__ hbf,
    uint4* __restrict__ aggz, int aggz_n,
    float4* __restrict__ pos_dst, const float4* __restrict__ pos_src,
    const int* __restrict__ erow, unsigned* __restrict__ cnt8)
{
    const int tid = threadIdx.x;
    if (PROJ_ON && (int)blockIdx.x < proj_nb) {
        __shared__ short hh[64][136];
        const int nb = blockIdx.x * 64;
        {
            const int rlane = tid & 15;
            const int row0  = tid >> 4;
            #pragma unroll
            for (int it = 0; it < 4; ++it) {
                int rr = row0 + it * 16;
                int node = nb + rr;
                if (node >= N_NODES) node = N_NODES - 1;
                const float4* src = (const float4*)&h[(size_t)node * H + rlane * 8];
                float4 a = src[0], b = src[1];
                bf16x8 v = { f2bf(a.x), f2bf(a.y), f2bf(a.z), f2bf(a.w),
                             f2bf(b.x), f2bf(b.y), f2bf(b.z), f2bf(b.w) };
                *(bf16x8*)&hh[rr][rlane * 8] = v;
            }
        }
        __syncthreads();

        const int lane = tid & 63;
        const int q    = lane >> 4;
        const int l15  = lane & 15;
        const int n0   = (tid >> 6) * 32;

        f32x4 accA[2][4] = {}, accB[2][4] = {};
        #pragma unroll
        for (int ks = 0; ks < 4; ++ks) {
            int k0 = ks * 32 + q * 8;
            bf16x8 wa0 = *(const bf16x8*)&W1b[(n0 + l15) * 264 + k0];
            bf16x8 wa1 = *(const bf16x8*)&W1b[(n0 + 16 + l15) * 264 + k0];
            bf16x8 wb0 = *(const bf16x8*)&W1b[(n0 + l15) * 264 + 128 + k0];
            bf16x8 wb1 = *(const bf16x8*)&W1b[(n0 + 16 + l15) * 264 + 128 + k0];
            bf16x8 e0 = *(const bf16x8*)&hh[l15][k0];
            bf16x8 e1 = *(const bf16x8*)&hh[16 + l15][k0];
            bf16x8 e2 = *(const bf16x8*)&hh[32 + l15][k0];
            bf16x8 e3 = *(const bf16x8*)&hh[48 + l15][k0];
            accA[0][0] = __builtin_amdgcn_mfma_f32_16x16x32_bf16(wa0, e0, accA[0][0], 0, 0, 0);
            accA[0][1] = __builtin_amdgcn_mfma_f32_16x16x32_bf16(wa0, e1, accA[0][1], 0, 0, 0);
            accA[0][2] = __builtin_amdgcn_mfma_f32_16x16x32_bf16(wa0, e2, accA[0][2], 0, 0, 0);
            accA[0][3] = __builtin_amdgcn_mfma_f32_16x16x32_bf16(wa0, e3, accA[0][3], 0, 0, 0);
            accA[1][0] = __builtin_amdgcn_mfma_f32_16x16x32_bf16(wa1, e0, accA[1][0], 0, 0, 0);
            accA[1][1] = __builtin_amdgcn_mfma_f32_16x16x32_bf16(wa1, e1, accA[1][1], 0, 0, 0);
            accA[1][2] = __builtin_amdgcn_mfma_f32_16x16x32_bf16(wa1, e2, accA[1][2], 0, 0, 0);
            accA[1][3] = __builtin_amdgcn_mfma_f32_16x16x32_bf16(wa1, e3, accA[1][3], 0, 0, 0);
            accB[0][0] = __builtin_amdgcn_mfma_f32_16x16x32_bf16(wb0, e0, accB[0][0], 0, 0, 0);
            accB[0][1] = __builtin_amdgcn_mfma_f32_16x16x32_bf16(wb0, e1, accB[0][1], 0, 0, 0);
            accB[0][2] = __builtin_amdgcn_mfma_f32_16x16x32_bf16(wb0, e2, accB[0][2], 0, 0, 0);
            accB[0][3] = __builtin_amdgcn_mfma_f32_16x16x32_bf16(wb0, e3, accB[0][3], 0, 0, 0);
            accB[1][0] = __builtin_amdgcn_mfma_f32_16x16x32_bf16(wb1, e0, accB[1][0], 0, 0, 0);
            accB[1][1] = __builtin_amdgcn_mfma_f32_16x16x32_bf16(wb1, e1, accB[1][1], 0, 0, 0);
            accB[1][2] = __builtin_amdgcn_mfma_f32_16x16x32_bf16(wb1, e2, accB[1][2], 0, 0, 0);
            accB[1][3] = __builtin_amdgcn_mfma_f32_16x16x32_bf16(wb1, e3, accB[1][3], 0, 0, 0);
        }

        #pragma unroll
        for (int ct = 0; ct < 2; ++ct) {
            float b1v[4];
            #pragma unroll
            for (int r = 0; r < 4; ++r) b1v[r] = be1[n0 + ct * 16 + q * 4 + r];
            #pragma unroll
            for (int et = 0; et < 4; ++et) {
                int node = nb + et * 16 + l15;
                if (node < N_NODES) {
                    int ch0 = n0 + ct * 16 + q * 4;
                    bf16x4 va, vb;
                    #pragma unroll
                    for (int r = 0; r < 4; ++r) {
                        va[r] = f2bf(accA[ct][et][r] + b1v[r]);
                        vb[r] = f2bf(accB[ct][et][r]);
                    }
                    *(bf16x4*)&Abf[(size_t)node * H + ch0] = va;
                    *(bf16x4*)&Bbf[(size_t)node * H + ch0] = vb;
                }
            }
        }
        return;
    }

    int i = ((int)blockIdx.x - proj_nb) * 256 + tid;
    if (i < nh4) {
        float4 v = ((const float4*)h)[i];
        bf16x4 s4 = { f2bf(v.x), f2bf(v.y), f2bf(v.z), f2bf(v.w) };
        *(bf16x4*)&hbf[i * 4] = s4;
        return;
    }
    i -= nh4;
    if (i < aggz_n) { aggz[i] = uint4{0u, 0u, 0u, 0u}; return; }
    i -= aggz_n;
    if (i < POS4) { pos_dst[i] = pos_src[i]; return; }
    i -= POS4;
    if (erow && i < N_EDGES)
        atomicAdd(&cnt8[(((unsigned)i >> 8) & 7) * CNT_PAD + erow[i]], 1u);
}

// ---- scan8: per-row fold of the 8 XCD sub-histograms; per-bucket bases
// in-place, deg row totals, block-exclusive offs, raw block sums ----
__global__ __launch_bounds__(256) void scan8(unsigned* __restrict__ cnt8,
                                             unsigned* __restrict__ offs,
                                             unsigned* __restrict__ deg,
                                             unsigned* __restrict__ bsum) {
    int t = threadIdx.x;
    int i = blockIdx.x * 256 + t;
    unsigned total = 0;
    if (i < N_NODES) {
        #pragma unroll
        for (int x = 0; x < 8; ++x) {
            unsigned c = cnt8[x * CNT_PAD + i];
            cnt8[x * CNT_PAD + i] = total;   // exclusive per-bucket base
            total += c;
        }
        deg[i] = total;
    }
    unsigned v = total;
    unsigned orig = v;
    #pragma unroll
    for (int d = 1; d < 64; d <<= 1) {
        unsigned n = __shfl_up(v, d);
        if ((t & 63) >= d) v += n;
    }
    __shared__ unsigned wsum[4], woff[4];
    if ((t & 63) == 63) wsum[t >> 6] = v;
    __syncthreads();
    if (t == 0) {
        unsigned r = 0;
        #pragma unroll
        for (int k = 0; k < 4; ++k) { woff[k] = r; r += wsum[k]; }
    }
    __syncthreads();
    unsigned incl = v + woff[t >> 6];
    offs[i] = incl - orig;
    if (t == 255) bsum[blockIdx.x] = incl;       // RAW block total
}

// ---- scatter: scan2 folded in; XCD-local atomic slot grab; PLAIN store ----
__global__ __launch_bounds__(256) void scatter_edges(const int* __restrict__ eidx,
        unsigned* __restrict__ cnt8, const unsigned* __restrict__ offs,
        const unsigned* __restrict__ bsum, int2* __restrict__ es) {
    __shared__ unsigned sb[256];
    __shared__ unsigned wsum[4], woff[4];
    int t = threadIdx.x;
    unsigned v = (t < NBS) ? bsum[t] : 0u;
    unsigned orig = v;
    #pragma unroll
    for (int d = 1; d < 64; d <<= 1) {
        unsigned n = __shfl_up(v, d);
        if ((t & 63) >= d) v += n;
    }
    if ((t & 63) == 63) wsum[t >> 6] = v;
    __syncthreads();
    if (t == 0) {
        unsigned r = 0;
        #pragma unroll
        for (int k = 0; k < 4; ++k) { woff[k] = r; r += wsum[k]; }
    }
    __syncthreads();
    sb[t] = v + woff[t >> 6] - orig;
    __syncthreads();
    int e = blockIdx.x * 256 + t;
    if (e < N_EDGES) {
        int r = eidx[e];
        int c = eidx[N_EDGES + e];
        unsigned x = (((unsigned)e >> 8) & 7) * CNT_PAD;   // same bucket as hist
        unsigned p = atomicAdd(&cnt8[x + r], 1u) + offs[r] + sb[r >> 8];
        es[p] = int2{r, c};
    }
}

// ---- main edge kernel: 128 edges / block, 512 threads (8 waves) ----
// EPB 64->128: halves per-edge cost of the serial tails (b0 init / pos
// phases where most threads idle) and barrier count. Waves 0-3 own edge
// half 0, waves 4-7 own half 1; T-flush stays 16 edges/wave. LDS 47.6KB
// -> 3 blocks x 8 waves = 24 waves/CU (same occupancy as the 256t/6blk
// config). t = silu(A[row]+B[col]+rn*w256) in the gather; T = sum(t)
// accumulated via sorted-run coalesced packed-bf16 bursts (GEMM2 folded
// into node kernel); GEMM3 (coord head, W3=Wc1@We2) only.
__global__ __launch_bounds__(512, 6) void edge_kernel2(
    const short* __restrict__ Abf, const short* __restrict__ Bbf,
    const float* __restrict__ pos,
    const int2* __restrict__ es,
    const float* __restrict__ w256f, const float* __restrict__ bc1p,
    const float* __restrict__ wc2f, const float* __restrict__ bc2,
    const short* __restrict__ W3b,
    unsigned* __restrict__ aggb,
    float* __restrict__ pos_out)
{
    __shared__ short s_t[EPB2][TSTR];     // 44032 B
    __shared__ float s_rn[EPB2];
    __shared__ float s_unit[EPB2][3];
    __shared__ int   s_row[EPB2];
    __shared__ int   s_col[EPB2];
    __shared__ float s_dot[EPB2];

    const int tid = threadIdx.x;

    int wg;
    {
        const int Q = NWG2 >> 3, R = NWG2 & 7;     // 781, 2
        int x = blockIdx.x & 7, k = blockIdx.x >> 3;
        int start = (x < R) ? x * (Q + 1) : R * (Q + 1) + (x - R) * Q;
        wg = start + k;
    }
    const int eb = wg * EPB2;

    if (tid < EPB2) {
        int2 rc = es[eb + tid];
        int r = rc.x, c = rc.y;
        s_row[tid] = r;
        s_col[tid] = c;
        float dx = pos[r*3+0] - pos[c*3+0];
        float dy = pos[r*3+1] - pos[c*3+1];
        float dz = pos[r*3+2] - pos[c*3+2];
        float nrm = sqrtf(dx*dx + dy*dy + dz*dz);
        float rn  = fmaxf(nrm, 1e-8f);
        s_rn[tid] = rn;
        s_unit[tid][0] = dx / rn;
        s_unit[tid][1] = dy / rn;
        s_unit[tid][2] = dz / rn;
        s_dot[tid] = 0.0f;
    }
    __syncthreads();   // b0

    const int lane = tid & 63;
    const int q    = lane >> 4;
    const int l15  = lane & 15;
    const int w    = tid >> 6;            // 0..7
    const int half = (w >> 2) * 64;       // edge-half base (0 or 64)
    const int n0   = (w & 3) * 32;        // channel base within half
    const int rlane = tid & 15;
    const int row0  = tid >> 4;           // 0..31

    // fused gather + elementwise -> t (512 threads cover 128 edges x 16 lanes)
    {
        float4 wv0 = *(const float4*)&w256f[rlane * 8];
        float4 wv1 = *(const float4*)&w256f[rlane * 8 + 4];
        float wv[8] = { wv0.x, wv0.y, wv0.z, wv0.w, wv1.x, wv1.y, wv1.z, wv1.w };
        #pragma unroll
        for (int it = 0; it < 4; ++it) {
            int e = row0 + it * 32;       // 0..127
            bf16x8 a = *(const bf16x8*)&Abf[(size_t)s_row[e] * H + rlane * 8];
            bf16x8 b = *(const bf16x8*)&Bbf[(size_t)s_col[e] * H + rlane * 8];
            float rn = s_rn[e];
            bf16x8 t8;
            #pragma unroll
            for (int j = 0; j < 8; ++j) {
                float x = bf2f(a[j]) + bf2f(b[j]) + rn * wv[j];
                t8[j] = f2bfr(silu(x));
            }
            *(bf16x8*)&s_t[e][rlane * 8] = t8;
        }
    }
    __syncthreads();   // b1: t ready

    // T flush FIRST (fire-and-forget atomics overlap GEMM3's MFMAs).
    // Wave w covers sorted edges w*16 .. w*16+15 -> run-reduced bursts.
    {
        const int base = w * 16;
        float a0 = 0.f, a1 = 0.f;
        int cur = s_row[base];
        #pragma unroll
        for (int i = 0; i < 16; ++i) {
            int nd = s_row[base + i];
            if (nd != cur) {
                unsigned pk = ((unsigned)(unsigned short)f2bfr(a0)) |
                              (((unsigned)(unsigned short)f2bfr(a1)) << 16);
                pk_agg_add(&aggb[(size_t)cur * 64 + lane], pk);
                a0 = 0.f; a1 = 0.f; cur = nd;
            }
            unsigned pr = *(const unsigned*)&s_t[base + i][lane * 2];
            a0 += __builtin_bit_cast(float, pr << 16);
            a1 += __builtin_bit_cast(float, pr & 0xFFFF0000u);
        }
        unsigned pk = ((unsigned)(unsigned short)f2bfr(a0)) |
                      (((unsigned)(unsigned short)f2bfr(a1)) << 16);
        pk_agg_add(&aggb[(size_t)cur * 64 + lane], pk);
    }

    // GEMM3: acc3 = W3@t for this wave's edge half; coord dot epilogue
    {
        f32x4 acc3[2][4] = {};
        #pragma unroll
        for (int ks = 0; ks < 4; ++ks) {
            int k0 = ks * 32 + q * 8;
            bf16x8 w30 = *(const bf16x8*)&W3b[(n0 + l15) * 128 + k0];
            bf16x8 w31 = *(const bf16x8*)&W3b[(n0 + 16 + l15) * 128 + k0];
            bf16x8 e0 = *(const bf16x8*)&s_t[half + l15][k0];
            bf16x8 e1 = *(const bf16x8*)&s_t[half + 16 + l15][k0];
            bf16x8 e2 = *(const bf16x8*)&s_t[half + 32 + l15][k0];
            bf16x8 e3 = *(const bf16x8*)&s_t[half + 48 + l15][k0];
            acc3[0][0] = __builtin_amdgcn_mfma_f32_16x16x32_bf16(w30, e0, acc3[0][0], 0, 0, 0);
            acc3[0][1] = __builtin_amdgcn_mfma_f32_16x16x32_bf16(w30, e1, acc3[0][1], 0, 0, 0);
            acc3[0][2] = __builtin_amdgcn_mfma_f32_16x16x32_bf16(w30, e2, acc3[0][2], 0, 0, 0);
            acc3[0][3] = __builtin_amdgcn_mfma_f32_16x16x32_bf16(w30, e3, acc3[0][3], 0, 0, 0);
            acc3[1][0] = __builtin_amdgcn_mfma_f32_16x16x32_bf16(w31, e0, acc3[1][0], 0, 0, 0);
            acc3[1][1] = __builtin_amdgcn_mfma_f32_16x16x32_bf16(w31, e1, acc3[1][1], 0, 0, 0);
            acc3[1][2] = __builtin_amdgcn_mfma_f32_16x16x32_bf16(w31, e2, acc3[1][2], 0, 0, 0);
            acc3[1][3] = __builtin_amdgcn_mfma_f32_16x16x32_bf16(w31, e3, acc3[1][3], 0, 0, 0);
        }
        float p[4] = {0.f, 0.f, 0.f, 0.f};
        #pragma unroll
        for (int ct = 0; ct < 2; ++ct)
            #pragma unroll
            for (int r = 0; r < 4; ++r) {
                int ch = n0 + ct * 16 + q * 4 + r;
                float bias = bc1p[ch];
                float w2   = wc2f[ch];
                #pragma unroll
                for (int et = 0; et < 4; ++et)
                    p[et] += silu(acc3[ct][et][r] + bias) * w2;
            }
        #pragma unroll
        for (int et = 0; et < 4; ++et) {
            float v = p[et];
            v += __shfl_xor(v, 16);
            v += __shfl_xor(v, 32);
            if (q == et) atomicAdd(&s_dot[half + et * 16 + l15], v);
        }
    }
    __syncthreads();   // b2: s_dot ready

    // ---- pos update: scale unit vectors, then run-reduce (sorted rows) ----
    if (tid < EPB2) {
        float s = tanhf(s_dot[tid] + bc2[0]) * 0.1f;
        s_unit[tid][0] *= s;
        s_unit[tid][1] *= s;
        s_unit[tid][2] *= s;
    }
    __syncthreads();   // b3: contribs ready
    if (tid < EPB2) {
        int r = s_row[tid];
        bool last = (tid == EPB2 - 1) || (s_row[tid + 1] != r);
        if (last) {
            float sx = 0.f, sy = 0.f, sz = 0.f;
            for (int j = tid; j >= 0 && s_row[j] == r; --j) {
                sx += s_unit[j][0];
                sy += s_unit[j][1];
                sz += s_unit[j][2];
            }
            atomicAdd(&pos_out[r * 3 + 0], sx);
            atomicAdd(&pos_out[r * 3 + 1], sy);
            atomicAdd(&pos_out[r * 3 + 2], sz);
        }
    }
}

// ---- fallback edge kernel: 64 edges / block, 256 threads (unsorted path;
// full GEMM1 + fused GEMM2/GEMM3 + m-based agg). Perf-irrelevant. ----
template<bool AGGBF16>
__global__ __launch_bounds__(256, 4) void edge_kernel_fb(
    const short* __restrict__ hbf, const float* __restrict__ pos,
    const int* __restrict__ rsrc, const int* __restrict__ csrc,
    const float* __restrict__ w256f, const float* __restrict__ be1,
    const float* __restrict__ be2, const float* __restrict__ bc1p,
    const float* __restrict__ wc2f, const float* __restrict__ bc2,
    const short* __restrict__ W1b, const short* __restrict__ W2b,
    const short* __restrict__ W3b,
    unsigned* __restrict__ aggb, float* __restrict__ aggf,
    float* __restrict__ pos_out)
{
    __shared__ short s_ein[EPB][264];
    __shared__ short s_t[EPB][136];
    __shared__ short s_m[EPB][136];
    __shared__ float s_rn[EPB];
    __shared__ float s_unit[EPB][3];
    __shared__ int   s_row[EPB];
    __shared__ int   s_col[EPB];
    __shared__ float s_dot[EPB];

    const int tid = threadIdx.x;
    const int eb  = blockIdx.x * EPB;

    if (tid < EPB) {
        int ge = eb + tid;
        int r = rsrc[ge], c = csrc[ge];
        s_row[tid] = r;
        s_col[tid] = c;
        float dx = pos[r*3+0] - pos[c*3+0];
        float dy = pos[r*3+1] - pos[c*3+1];
        float dz = pos[r*3+2] - pos[c*3+2];
        float nrm = sqrtf(dx*dx + dy*dy + dz*dz);
        float rn  = fmaxf(nrm, 1e-8f);
        s_rn[tid] = rn;
        s_unit[tid][0] = dx / rn;
        s_unit[tid][1] = dy / rn;
        s_unit[tid][2] = dz / rn;
        s_dot[tid] = 0.0f;
    }
    __syncthreads();

    const int lane = tid & 63;
    const int q    = lane >> 4;
    const int l15  = lane & 15;
    const int n0   = (tid >> 6) * 32;
    const int w    = tid >> 6;
    const int rlane = tid & 15;
    const int row0  = tid >> 4;

    #pragma unroll
    for (int it = 0; it < 8; ++it) {
        int rr = row0 + it * 16;
        int e  = rr & 63, sg = rr >> 6;
        int idx = sg ? s_col[e] : s_row[e];
        bf16x8 v = *(const bf16x8*)&hbf[(size_t)idx * H + rlane * 8];
        *(bf16x8*)&s_ein[e][sg * 128 + rlane * 8] = v;
    }
    __syncthreads();

    f32x4 acc[2][4] = {};
    #pragma unroll
    for (int ks = 0; ks < 8; ++ks) {
        int k0 = ks * 32 + q * 8;
        bf16x8 w0 = *(const bf16x8*)&W1b[(n0 + l15) * 264 + k0];
        bf16x8 w1 = *(const bf16x8*)&W1b[(n0 + 16 + l15) * 264 + k0];
        bf16x8 e0 = *(const bf16x8*)&s_ein[l15][k0];
        bf16x8 e1 = *(const bf16x8*)&s_ein[16 + l15][k0];
        bf16x8 e2 = *(const bf16x8*)&s_ein[32 + l15][k0];
        bf16x8 e3 = *(const bf16x8*)&s_ein[48 + l15][k0];
        acc[0][0] = __builtin_amdgcn_mfma_f32_16x16x32_bf16(w0, e0, acc[0][0], 0, 0, 0);
        acc[0][1] = __builtin_amdgcn_mfma_f32_16x16x32_bf16(w0, e1, acc[0][1], 0, 0, 0);
        acc[0][2] = __builtin_amdgcn_mfma_f32_16x16x32_bf16(w0, e2, acc[0][2], 0, 0, 0);
        acc[0][3] = __builtin_amdgcn_mfma_f32_16x16x32_bf16(w0, e3, acc[0][3], 0, 0, 0);
        acc[1][0] = __builtin_amdgcn_mfma_f32_16x16x32_bf16(w1, e0, acc[1][0], 0, 0, 0);
        acc[1][1] = __builtin_amdgcn_mfma_f32_16x16x32_bf16(w1, e1, acc[1][1], 0, 0, 0);
        acc[1][2] = __builtin_amdgcn_mfma_f32_16x16x32_bf16(w1, e2, acc[1][2], 0, 0, 0);
        acc[1][3] = __builtin_amdgcn_mfma_f32_16x16x32_bf16(w1, e3, acc[1][3], 0, 0, 0);
    }
    {
        float w256v[2][4], b1v[2][4], rn_e[4];
        #pragma unroll
        for (int ct = 0; ct < 2; ++ct)
            #pragma unroll
            for (int r = 0; r < 4; ++r) {
                int ch = n0 + ct * 16 + q * 4 + r;
                w256v[ct][r] = w256f[ch];
                b1v[ct][r]   = be1[ch];
            }
        #pragma unroll
        for (int et = 0; et < 4; ++et) rn_e[et] = s_rn[et * 16 + l15];
        #pragma unroll
        for (int ct = 0; ct < 2; ++ct)
            #pragma unroll
            for (int et = 0; et < 4; ++et) {
                bf16x4 v;
                #pragma unroll
                for (int r = 0; r < 4; ++r)
                    v[r] = f2bfr(silu(acc[ct][et][r] + rn_e[et] * w256v[ct][r] + b1v[ct][r]));
                *(bf16x4*)&s_t[et * 16 + l15][n0 + ct * 16 + q * 4] = v;
            }
    }
    __syncthreads();

    f32x4 acc2[2][4] = {}, acc3[2][4] = {};
    #pragma unroll
    for (int ks = 0; ks < 4; ++ks) {
        int k0 = ks * 32 + q * 8;
        bf16x8 w20 = *(const bf16x8*)&W2b[(n0 + l15) * 128 + k0];
        bf16x8 w21 = *(const bf16x8*)&W2b[(n0 + 16 + l15) * 128 + k0];
        bf16x8 w30 = *(const bf16x8*)&W3b[(n0 + l15) * 128 + k0];
        bf16x8 w31 = *(const bf16x8*)&W3b[(n0 + 16 + l15) * 128 + k0];
        bf16x8 e0 = *(const bf16x8*)&s_t[l15][k0];
        bf16x8 e1 = *(const bf16x8*)&s_t[16 + l15][k0];
        bf16x8 e2 = *(const bf16x8*)&s_t[32 + l15][k0];
        bf16x8 e3 = *(const bf16x8*)&s_t[48 + l15][k0];
        acc2[0][0] = __builtin_amdgcn_mfma_f32_16x16x32_bf16(w20, e0, acc2[0][0], 0, 0, 0);
        acc2[0][1] = __builtin_amdgcn_mfma_f32_16x16x32_bf16(w20, e1, acc2[0][1], 0, 0, 0);
        acc2[0][2] = __builtin_amdgcn_mfma_f32_16x16x32_bf16(w20, e2, acc2[0][2], 0, 0, 0);
        acc2[0][3] = __builtin_amdgcn_mfma_f32_16x16x32_bf16(w20, e3, acc2[0][3], 0, 0, 0);
        acc2[1][0] = __builtin_amdgcn_mfma_f32_16x16x32_bf16(w21, e0, acc2[1][0], 0, 0, 0);
        acc2[1][1] = __builtin_amdgcn_mfma_f32_16x16x32_bf16(w21, e1, acc2[1][1], 0, 0, 0);
        acc2[1][2] = __builtin_amdgcn_mfma_f32_16x16x32_bf16(w21, e2, acc2[1][2], 0, 0, 0);
        acc2[1][3] = __builtin_amdgcn_mfma_f32_16x16x32_bf16(w21, e3, acc2[1][3], 0, 0, 0);
        acc3[0][0] = __builtin_amdgcn_mfma_f32_16x16x32_bf16(w30, e0, acc3[0][0], 0, 0, 0);
        acc3[0][1] = __builtin_amdgcn_mfma_f32_16x16x32_bf16(w30, e1, acc3[0][1], 0, 0, 0);
        acc3[0][2] = __builtin_amdgcn_mfma_f32_16x16x32_bf16(w30, e2, acc3[0][2], 0, 0, 0);
        acc3[0][3] = __builtin_amdgcn_mfma_f32_16x16x32_bf16(w30, e3, acc3[0][3], 0, 0, 0);
        acc3[1][0] = __builtin_amdgcn_mfma_f32_16x16x32_bf16(w31, e0, acc3[1][0], 0, 0, 0);
        acc3[1][1] = __builtin_amdgcn_mfma_f32_16x16x32_bf16(w31, e1, acc3[1][1], 0, 0, 0);
        acc3[1][2] = __builtin_amdgcn_mfma_f32_16x16x32_bf16(w31, e2, acc3[1][2], 0, 0, 0);
        acc3[1][3] = __builtin_amdgcn_mfma_f32_16x16x32_bf16(w31, e3, acc3[1][3], 0, 0, 0);
    }
    {
        float b2v[2][4];
        #pragma unroll
        for (int ct = 0; ct < 2; ++ct)
            #pragma unroll
            for (int r = 0; r < 4; ++r)
                b2v[ct][r] = be2[n0 + ct * 16 + q * 4 + r];
        #pragma unroll
        for (int ct = 0; ct < 2; ++ct)
            #pragma unroll
            for (int et = 0; et < 4; ++et) {
                bf16x4 v;
                #pragma unroll
                for (int r = 0; r < 4; ++r)
                    v[r] = f2bfr(acc2[ct][et][r] + b2v[ct][r]);
                *(bf16x4*)&s_m[et * 16 + l15][n0 + ct * 16 + q * 4] = v;
            }
    }
    {
        float p[4] = {0.f, 0.f, 0.f, 0.f};
        #pragma unroll
        for (int ct = 0; ct < 2; ++ct)
            #pragma unroll
            for (int r = 0; r < 4; ++r) {
                int ch = n0 + ct * 16 + q * 4 + r;
                float bias = bc1p[ch];
                float w2   = wc2f[ch];
                #pragma unroll
                for (int et = 0; et < 4; ++et)
                    p[et] += silu(acc3[ct][et][r] + bias) * w2;
            }
        #pragma unroll
        for (int et = 0; et < 4; ++et) {
            float v = p[et];
            v += __shfl_xor(v, 16);
            v += __shfl_xor(v, 32);
            if (q == et) atomicAdd(&s_dot[et * 16 + l15], v);
        }
    }
    __syncthreads();

    if constexpr (AGGBF16) {
        #pragma unroll
        for (int i = 0; i < 16; ++i) {
            int row = w + i * 4;
            unsigned pr = *(const unsigned*)&s_m[row][lane * 2];
            pk_agg_add(&aggb[(size_t)s_row[row] * 64 + lane], pr);
        }
    } else {
        #pragma unroll
        for (int i = 0; i < 16; ++i) {
            int row = w + i * 4;
            unsigned pr = *(const unsigned*)&s_m[row][lane * 2];
            float f0 = __builtin_bit_cast(float, pr << 16);
            float f1 = __builtin_bit_cast(float, pr & 0xFFFF0000u);
            float* dst = &aggf[(size_t)s_row[row] * H + 2 * lane];
            atomicAdd(dst, f0);
            atomicAdd(dst + 1, f1);
        }
    }

    if (tid < EPB) {
        float s = tanhf(s_dot[tid] + bc2[0]) * 0.1f;
        int r = s_row[tid];
        atomicAdd(&pos_out[r * 3 + 0], s * s_unit[tid][0]);
        atomicAdd(&pos_out[r * 3 + 1], s * s_unit[tid][1]);
        atomicAdd(&pos_out[r * 3 + 2], s * s_unit[tid][2]);
    }
}

// ---- node kernel: 64 nodes / block. FOLD: input is [h | T], Wn1b's agg
// columns hold Wfold = Wn1[:,128:]@We2, plus per-node deg*bfold bias. ----
template<bool AGGBF16, bool FOLD>
__global__ __launch_bounds__(256) void node_kernel(
    const float* __restrict__ h,
    const unsigned short* __restrict__ aggb, const float* __restrict__ aggf,
    const unsigned* __restrict__ deg, const float* __restrict__ bfold,
    const float* __restrict__ bn1, const float* __restrict__ bn2,
    const short* __restrict__ Wn1b, const short* __restrict__ Wn2b,
    float* __restrict__ hout)
{
    __shared__ short s_a[64][264];
    __shared__ short s_t[64][136];

    const int tid = threadIdx.x;
    const int nb  = blockIdx.x * 64;

    {
        const int rlane = tid & 15;
        const int row0  = tid >> 4;
        #pragma unroll
        for (int it = 0; it < 8; ++it) {
            int rr = row0 + it * 16;
            int e  = rr & 63, sg = rr >> 6;
            int node = nb + e;
            if (node >= N_NODES) node = N_NODES - 1;
            bf16x8 v;
            if (sg == 0) {
                const float4* src = (const float4*)&h[(size_t)node * H + rlane * 8];
                float4 a = src[0], b = src[1];
                v = bf16x8{ f2bf(a.x), f2bf(a.y), f2bf(a.z), f2bf(a.w),
                            f2bf(b.x), f2bf(b.y), f2bf(b.z), f2bf(b.w) };
            } else if constexpr (AGGBF16) {
                v = *(const bf16x8*)&aggb[(size_t)node * H + rlane * 8];
            } else {
                const float* src = &aggf[(size_t)node * H + rlane * 8];
                bf16x8 t;
                #pragma unroll
                for (int j = 0; j < 8; ++j) t[j] = f2bfr(src[j]);
                v = t;
            }
            *(bf16x8*)&s_a[e][sg * 128 + rlane * 8] = v;
        }
    }
    __syncthreads();

    const int lane = tid & 63;
    const int q    = lane >> 4;
    const int l15  = lane & 15;
    const int n0   = (tid >> 6) * 32;

    f32x4 acc[2][4] = {};
    #pragma unroll
    for (int ks = 0; ks < 8; ++ks) {
        int k0 = ks * 32 + q * 8;
        bf16x8 w0 = *(const bf16x8*)&Wn1b[(n0 + l15) * 264 + k0];
        bf16x8 w1 = *(const bf16x8*)&Wn1b[(n0 + 16 + l15) * 264 + k0];
        bf16x8 e0 = *(const bf16x8*)&s_a[l15][k0];
        bf16x8 e1 = *(const bf16x8*)&s_a[16 + l15][k0];
        bf16x8 e2 = *(const bf16x8*)&s_a[32 + l15][k0];
        bf16x8 e3 = *(const bf16x8*)&s_a[48 + l15][k0];
        acc[0][0] = __builtin_amdgcn_mfma_f32_16x16x32_bf16(w0, e0, acc[0][0], 0, 0, 0);
        acc[0][1] = __builtin_amdgcn_mfma_f32_16x16x32_bf16(w0, e1, acc[0][1], 0, 0, 0);
        acc[0][2] = __builtin_amdgcn_mfma_f32_16x16x32_bf16(w0, e2, acc[0][2], 0, 0, 0);
        acc[0][3] = __builtin_amdgcn_mfma_f32_16x16x32_bf16(w0, e3, acc[0][3], 0, 0, 0);
        acc[1][0] = __builtin_amdgcn_mfma_f32_16x16x32_bf16(w1, e0, acc[1][0], 0, 0, 0);
        acc[1][1] = __builtin_amdgcn_mfma_f32_16x16x32_bf16(w1, e1, acc[1][1], 0, 0, 0);
        acc[1][2] = __builtin_amdgcn_mfma_f32_16x16x32_bf16(w1, e2, acc[1][2], 0, 0, 0);
        acc[1][3] = __builtin_amdgcn_mfma_f32_16x16x32_bf16(w1, e3, acc[1][3], 0, 0, 0);
    }
    {
        float b1v[2][4], bf_v[2][4], degf[4];
        #pragma unroll
        for (int ct = 0; ct < 2; ++ct)
            #pragma unroll
            for (int r = 0; r < 4; ++r) {
                int ch = n0 + ct * 16 + q * 4 + r;
                b1v[ct][r] = bn1[ch];
                if constexpr (FOLD) bf_v[ct][r] = bfold[ch];
            }
        if constexpr (FOLD) {
            #pragma unroll
            for (int et = 0; et < 4; ++et) {
                int node = nb + et * 16 + l15;
                if (node >= N_NODES) node = N_NODES - 1;
                degf[et] = (float)deg[node];
            }
        }
        #pragma unroll
        for (int ct = 0; ct < 2; ++ct)
            #pragma unroll
            for (int et = 0; et < 4; ++et) {
                bf16x4 v;
                #pragma unroll
                for (int r = 0; r < 4; ++r) {
                    float x = acc[ct][et][r] + b1v[ct][r];
                    if constexpr (FOLD) x += degf[et] * bf_v[ct][r];
                    v[r] = f2bfr(silu(x));
                }
                *(bf16x4*)&s_t[et * 16 + l15][n0 + ct * 16 + q * 4] = v;
            }
    }
    __syncthreads();

    f32x4 acc2[2][4] = {};
    #pragma unroll
    for (int ks = 0; ks < 4; ++ks) {
        int k0 = ks * 32 + q * 8;
        bf16x8 w0 = *(const bf16x8*)&Wn2b[(n0 + l15) * 128 + k0];
        bf16x8 w1 = *(const bf16x8*)&Wn2b[(n0 + 16 + l15) * 128 + k0];
        bf16x8 e0 = *(const bf16x8*)&s_t[l15][k0];
        bf16x8 e1 = *(const bf16x8*)&s_t[16 + l15][k0];
        bf16x8 e2 = *(const bf16x8*)&s_t[32 + l15][k0];
        bf16x8 e3 = *(const bf16x8*)&s_t[48 + l15][k0];
        acc2[0][0] = __builtin_amdgcn_mfma_f32_16x16x32_bf16(w0, e0, acc2[0][0], 0, 0, 0);
        acc2[0][1] = __builtin_amdgcn_mfma_f32_16x16x32_bf16(w0, e1, acc2[0][1], 0, 0, 0);
        acc2[0][2] = __builtin_amdgcn_mfma_f32_16x16x32_bf16(w0, e2, acc2[0][2], 0, 0, 0);
        acc2[0][3] = __builtin_amdgcn_mfma_f32_16x16x32_bf16(w0, e3, acc2[0][3], 0, 0, 0);
        acc2[1][0] = __builtin_amdgcn_mfma_f32_16x16x32_bf16(w1, e0, acc2[1][0], 0, 0, 0);
        acc2[1][1] = __builtin_amdgcn_mfma_f32_16x16x32_bf16(w1, e1, acc2[1][1], 0, 0, 0);
        acc2[1][2] = __builtin_amdgcn_mfma_f32_16x16x32_bf16(w1, e2, acc2[1][2], 0, 0, 0);
        acc2[1][3] = __builtin_amdgcn_mfma_f32_16x16x32_bf16(w1, e3, acc2[1][3], 0, 0, 0);
    }
    {
        float b2v[2][4];
        #pragma unroll
        for (int ct = 0; ct < 2; ++ct)
            #pragma unroll
            for (int r = 0; r < 4; ++r)
                b2v[ct][r] = bn2[n0 + ct * 16 + q * 4 + r];
        #pragma unroll
        for (int ct = 0; ct < 2; ++ct)
            #pragma unroll
            for (int et = 0; et < 4; ++et) {
                int node = nb + et * 16 + l15;
                if (node < N_NODES) {
                    int ch0 = n0 + ct * 16 + q * 4;
                    const float4 hres = *(const float4*)&h[(size_t)node * H + ch0];
                    float4 o;
                    o.x = acc2[ct][et][0] + b2v[ct][0] + hres.x;
                    o.y = acc2[ct][et][1] + b2v[ct][1] + hres.y;
                    o.z = acc2[ct][et][2] + b2v[ct][2] + hres.z;
                    o.w = acc2[ct][et][3] + b2v[ct][3] + hres.w;
                    *(float4*)&hout[(size_t)node * H + ch0] = o;
                }
            }
    }
}

extern "C" void kernel_launch(void* const* d_in, const int* in_sizes, int n_in,
                              void* d_out, int out_size, void* d_ws, size_t ws_size,
                              hipStream_t stream) {
    const float* h   = (const float*)d_in[0];
    const float* pos = (const float*)d_in[1];
    const int*  eidx = (const int*)d_in[2];
    const float* We1 = (const float*)d_in[3];
    const float* be1 = (const float*)d_in[4];
    const float* We2 = (const float*)d_in[5];
    const float* be2 = (const float*)d_in[6];
    const float* Wn1 = (const float*)d_in[7];
    const float* bn1 = (const float*)d_in[8];
    const float* Wn2 = (const float*)d_in[9];
    const float* bn2 = (const float*)d_in[10];
    const float* Wc1 = (const float*)d_in[11];
    const float* bc1 = (const float*)d_in[12];
    const float* Wc2 = (const float*)d_in[13];
    const float* bc2 = (const float*)d_in[14];

    float* out_h   = (float*)d_out;
    float* out_pos = out_h + (size_t)N_NODES * H;

    char* ws = (char*)d_ws;
    short* W1b  = (short*)(ws);
    short* W2b  = (short*)(ws + 2 * P_W1);
    short* W3b  = (short*)(ws + 2 * (P_W1 + P_W2));
    short* Wn1b = (short*)(ws + 2 * (P_W1 + 2 * P_W2));
    short* Wn2b = (short*)(ws + 2 * (2 * P_W1 + 2 * P_W2));
    float* w256f = (float*)(ws + 2 * (size_t)(2 * P_W1 + 3 * P_W2));
    float* bc1p  = w256f + 128;
    float* bfold = w256f + 256;
    const size_t WSW = 2 * (size_t)(2 * P_W1 + 3 * P_W2) + 2048;
    const size_t HBF = (size_t)N_NODES * H * 2;             // 12.8 MB
    const size_t AGG = (size_t)N_NODES * H * 2;             // 12.8 MB (T or agg)
    const size_t CNT8B = (size_t)8 * CNT_PAD * 4;           // 1.6 MB per-XCD hist
    const size_t OFFB = (size_t)CNT_PAD * 4;
    const size_t DEGB = (size_t)CNT_PAD * 4;
    const size_t BSB  = 256 * 4;
    const size_t ESB  = (size_t)N_EDGES * 8;                // 6.4 MB int2
    const size_t PRJ  = (size_t)N_NODES * H * 2;            // 12.8 MB each
    short* hbf = (short*)(ws + WSW);
    const bool use_bf16 = (ws_size >= WSW + HBF + AGG);
    const bool use_proj = (ws_size >= WSW + HBF + AGG + CNT8B + OFFB + DEGB + BSB + ESB + 2 * PRJ);

    const int PW_N = P_TOT + 128 + NW3 + 128 + 128;  // weights+w256+W3+bc1p+bfold

    if (use_bf16 && use_proj) {
        unsigned* aggb = (unsigned*)(ws + WSW + HBF);
        unsigned* cnt8 = (unsigned*)(ws + WSW + HBF + AGG);
        unsigned* offs = (unsigned*)((char*)cnt8 + CNT8B);
        unsigned* deg  = (unsigned*)((char*)offs + OFFB);
        unsigned* bsum = (unsigned*)((char*)deg + DEGB);
        int2* es = (int2*)((char*)bsum + BSB);
        short* Abf = (short*)((char*)es + ESB);
        short* Bbf = (short*)((char*)Abf + PRJ);

        prep_w<<<(PW_N + 8 * CNT_PAD + 255) / 256, 256, 0, stream>>>(
            We1, We2, Wc1, be2, bc1, Wn1, Wn2,
            W1b, W2b, W3b, Wn1b, Wn2b, w256f, bc1p, bfold,
            cnt8, 8 * CNT_PAD, 1);
        const int rest = AGG16 + POS4 + N_EDGES;
        prep2<true><<<PROJ_NB + (rest + 255) / 256, 256, 0, stream>>>(
            PROJ_NB, h, W1b, be1, Abf, Bbf, 0, nullptr,
            (uint4*)aggb, AGG16, (float4*)out_pos, (const float4*)pos,
            eidx, cnt8);
        scan8<<<NBS, 256, 0, stream>>>(cnt8, offs, deg, bsum);
        scatter_edges<<<(N_EDGES + 255) / 256, 256, 0, stream>>>(
            eidx, cnt8, offs, bsum, es);
        edge_kernel2<<<NWG2, 512, 0, stream>>>(
            Abf, Bbf, pos, es, w256f, bc1p, Wc2, bc2, W3b, aggb, out_pos);
        node_kernel<true, true><<<(N_NODES + 63) / 64, 256, 0, stream>>>(
            h, (const unsigned short*)aggb, nullptr, deg, bfold,
            bn1, bn2, Wn1b, Wn2b, out_h);
    } else if (use_bf16) {
        unsigned* aggb = (unsigned*)(ws + WSW + HBF);
        prep_w<<<(PW_N + 255) / 256, 256, 0, stream>>>(
            We1, We2, Wc1, be2, bc1, Wn1, Wn2,
            W1b, W2b, W3b, Wn1b, Wn2b, w256f, bc1p, bfold,
            nullptr, 0, 0);
        const int rest = NH4 + AGG16 + POS4;
        prep2<false><<<(rest + 255) / 256, 256, 0, stream>>>(
            0, h, nullptr, nullptr, nullptr, nullptr, NH4, hbf,
            (uint4*)aggb, AGG16, (float4*)out_pos, (const float4*)pos,
            nullptr, nullptr);
        edge_kernel_fb<true><<<NWG_EDGE, 256, 0, stream>>>(
            hbf, pos, eidx, eidx + N_EDGES,
            w256f, be1, be2, bc1p, Wc2, bc2,
            W1b, W2b, W3b, aggb, nullptr, out_pos);
        node_kernel<true, false><<<(N_NODES + 63) / 64, 256, 0, stream>>>(
            h, (const unsigned short*)aggb, nullptr, nullptr, nullptr,
            bn1, bn2, Wn1b, Wn2b, out_h);
    } else {
        // fallback: f32 agg in d_out h region
        prep_w<<<(PW_N + 255) / 256, 256, 0, stream>>>(
            We1, We2, Wc1, be2, bc1, Wn1, Wn2,
            W1b, W2b, W3b, Wn1b, Wn2b, w256f, bc1p, bfold,
            nullptr, 0, 0);
        const int rest = NH4 + POS4;
        prep2<false><<<(rest + 255) / 256, 256, 0, stream>>>(
            0, h, nullptr, nullptr, nullptr, nullptr, NH4, hbf,
            nullptr, 0, (float4*)out_pos, (const float4*)pos,
            nullptr, nullptr);
        hipMemsetAsync(out_h, 0, (size_t)N_NODES * H * sizeof(float), stream);
        edge_kernel_fb<false><<<NWG_EDGE, 256, 0, stream>>>(
            hbf, pos, eidx, eidx + N_EDGES,
            w256f, be1, be2, bc1p, Wc2, bc2,
            W1b, W2b, W3b, nullptr, out_h, out_pos);
        node_kernel<false, false><<<(N_NODES + 63) / 64, 256, 0, stream>>>(
            h, nullptr, out_h, nullptr, nullptr, bn1, bn2, Wn1b, Wn2b, out_h);
    }
}

// Round 13
// 329.820 us; speedup vs baseline: 1.0404x; 1.0404x over previous
//
#include <hip/hip_runtime.h>
#include <math.h>

#define N_NODES 50000
#define N_EDGES 800000
#define H 128
#define EIN 257
#define EPB 64   // edges per block
#define NWG_EDGE (N_EDGES / EPB)     // 12500
#define CNT_PAD 50176                // 196*256
#define NBS 196                      // scan blocks

typedef short bf16x8 __attribute__((ext_vector_type(8)));
typedef short bf16x4 __attribute__((ext_vector_type(4)));
typedef short bf16x2 __attribute__((ext_vector_type(2)));
typedef float f32x4 __attribute__((ext_vector_type(4)));

static __device__ __forceinline__ short f2bf(float x) {
    unsigned u = __builtin_bit_cast(unsigned, x);
    unsigned r = (u + 0x7FFFu + ((u >> 16) & 1u)) >> 16;
    return (short)r;
}

static __device__ __forceinline__ short f2bfr(float x) {
    return (short)((__builtin_bit_cast(unsigned, x) + 0x8000u) >> 16);
}

static __device__ __forceinline__ float bf2f(short s) {
    return __builtin_bit_cast(float, ((unsigned)(unsigned short)s) << 16);
}

static __device__ __forceinline__ float silu(float x) {
#if __has_builtin(__builtin_amdgcn_rcpf)
    return x * __builtin_amdgcn_rcpf(1.0f + __expf(-x));
#else
    return x / (1.0f + __expf(-x));
#endif
}

static __device__ __forceinline__ void pk_agg_add(unsigned* addr, unsigned val) {
#if __has_builtin(__builtin_amdgcn_global_atomic_fadd_v2bf16)
    bf16x2 v = __builtin_bit_cast(bf16x2, val);
    (void)__builtin_amdgcn_global_atomic_fadd_v2bf16(
        (__attribute__((address_space(1))) bf16x2*)(unsigned long long)addr, v);
#else
    asm volatile("global_atomic_pk_add_bf16 %0, %1, off"
                 :: "v"(addr), "v"(val) : "memory");
#endif
}

#define P_W1  (128*264)
#define P_W2  (128*128)
#define P_TOT (2*(P_W1 + P_W2))
#define NH4   (N_NODES * H / 4)
#define AGG16 (N_NODES * H * 2 / 16)
#define POS4  ((N_NODES * 3 + 3) / 4)
#define NW3   (128*128)
#define PROJ_NB ((N_NODES + 63) / 64)    // 782
#define TSTR  172   // s_t row stride (shorts): LDS 23.8KB -> 6 blocks/CU.
                    // R10 A/B: same time as 8/CU but WRITE 152->27MB (no L2
                    // thrash), conflicts halved. Keep: neutral time, clean L2.

// NT-hint policy (R8+R10 lessons): NO nontemporal loads/stores anywhere.
// NT on gathers with L2 reuse drops hit rate (+18us); NT on dense-but-random
// 8B stores defeats L2 write-combining (+8us). Plain accesses win everywhere.
// Block-size lesson (R12): EPB=128/512t regressed +12us (barrier scope +
// serial pos-scan length + fewer blocks to overlap); keep 64/256t.

// ---- prep_w: weight conversions, W3 = Wc1@We2, bc1p, Wfold (inline into
// Wn1b cols 128..255 when fold), bfold = Wn1[:,128:]@be2, cnt8 zero ----
__global__ __launch_bounds__(256) void prep_w(
    const float* __restrict__ We1, const float* __restrict__ We2,
    const float* __restrict__ Wc1, const float* __restrict__ be2,
    const float* __restrict__ bc1,
    const float* __restrict__ Wn1, const float* __restrict__ Wn2,
    short* __restrict__ W1b, short* __restrict__ W2b, short* __restrict__ W3b,
    short* __restrict__ Wn1b, short* __restrict__ Wn2b,
    float* __restrict__ w256f, float* __restrict__ bc1p,
    float* __restrict__ bfold,
    unsigned* __restrict__ cnt, int cntn, int fold)
{
    int i = blockIdx.x * 256 + threadIdx.x;
    if (i < P_TOT) {
        if (i < P_W1) {
            int j = i / 264, k = i % 264;
            W1b[i] = (k < EIN) ? f2bf(We1[j * EIN + k]) : (short)0;
        } else if (i < P_W1 + P_W2) {
            int t = i - P_W1;
            W2b[t] = f2bf(We2[t]);
        } else if (i < 2 * P_W1 + P_W2) {
            int t = i - P_W1 - P_W2;
            int j = t / 264, k = t % 264;
            short v;
            if (k < 128) v = f2bf(Wn1[j * 256 + k]);
            else if (k < 256) {
                if (fold) {           // Wfold = Wn1[:,128:] @ We2
                    const float* wr = &Wn1[j * 256 + 128];
                    const float* wc = &We2[k - 128];
                    float acc = 0.f;
                    #pragma unroll 8
                    for (int o = 0; o < 128; ++o) acc += wr[o] * wc[o * 128];
                    v = f2bf(acc);
                } else v = f2bf(Wn1[j * 256 + k]);
            } else v = 0;
            Wn1b[t] = v;
        } else {
            int t = i - 2 * P_W1 - P_W2;
            Wn2b[t] = f2bf(Wn2[t]);
        }
        return;
    }
    i -= P_TOT;
    if (i < 128) { w256f[i] = We1[i * EIN + 256]; return; }
    i -= 128;
    if (i < NW3) {                       // W3 = Wc1 @ We2
        int j = i >> 7, k = i & 127;
        const float* wr = &Wc1[j * 128];
        float acc = 0.f;
        #pragma unroll 8
        for (int o = 0; o < 128; ++o)
            acc += wr[o] * We2[o * 128 + k];
        W3b[i] = f2bf(acc);
        return;
    }
    i -= NW3;
    if (i < 128) {                       // bc1p = bc1 + Wc1 @ be2
        const float* wr = &Wc1[i * 128];
        float acc = bc1[i];
        #pragma unroll 8
        for (int o = 0; o < 128; ++o) acc += wr[o] * be2[o];
        bc1p[i] = acc;
        return;
    }
    i -= 128;
    if (i < 128) {                       // bfold = Wn1[:,128:] @ be2
        const float* wr = &Wn1[i * 256 + 128];
        float acc = 0.f;
        #pragma unroll 8
        for (int o = 0; o < 128; ++o) acc += wr[o] * be2[o];
        bfold[i] = acc;
        return;
    }
    i -= 128;
    if (cnt && i < cntn) cnt[i] = 0u;
}

// ---- prep2: proj blocks + streaming rest in ONE dispatch.
// Histogram XCD-PRIVATIZED: bucket x = (edge>>8)&7 == physical XCD of the
// processing block (round-robin dispatch) -> atomics resolve in local L2. ----
template<bool PROJ_ON>
__global__ __launch_bounds__(256) void prep2(
    int proj_nb,
    const float* __restrict__ h, const short* __restrict__ W1b,
    const float* __restrict__ be1,
    short* __restrict__ Abf, short* __restrict__ Bbf,
    int nh4, short* __restrict__ hbf,
    uint4* __restrict__ aggz, int aggz_n,
    float4* __restrict__ pos_dst, const float4* __restrict__ pos_src,
    const int* __restrict__ erow, unsigned* __restrict__ cnt8)
{
    const int tid = threadIdx.x;
    if (PROJ_ON && (int)blockIdx.x < proj_nb) {
        __shared__ short hh[64][136];
        const int nb = blockIdx.x * 64;
        {
            const int rlane = tid & 15;
            const int row0  = tid >> 4;
            #pragma unroll
            for (int it = 0; it < 4; ++it) {
                int rr = row0 + it * 16;
                int node = nb + rr;
                if (node >= N_NODES) node = N_NODES - 1;
                const float4* src = (const float4*)&h[(size_t)node * H + rlane * 8];
                float4 a = src[0], b = src[1];
                bf16x8 v = { f2bf(a.x), f2bf(a.y), f2bf(a.z), f2bf(a.w),
                             f2bf(b.x), f2bf(b.y), f2bf(b.z), f2bf(b.w) };
                *(bf16x8*)&hh[rr][rlane * 8] = v;
            }
        }
        __syncthreads();

        const int lane = tid & 63;
        const int q    = lane >> 4;
        const int l15  = lane & 15;
        const int n0   = (tid >> 6) * 32;

        f32x4 accA[2][4] = {}, accB[2][4] = {};
        #pragma unroll
        for (int ks = 0; ks < 4; ++ks) {
            int k0 = ks * 32 + q * 8;
            bf16x8 wa0 = *(const bf16x8*)&W1b[(n0 + l15) * 264 + k0];
            bf16x8 wa1 = *(const bf16x8*)&W1b[(n0 + 16 + l15) * 264 + k0];
            bf16x8 wb0 = *(const bf16x8*)&W1b[(n0 + l15) * 264 + 128 + k0];
            bf16x8 wb1 = *(const bf16x8*)&W1b[(n0 + 16 + l15) * 264 + 128 + k0];
            bf16x8 e0 = *(const bf16x8*)&hh[l15][k0];
            bf16x8 e1 = *(const bf16x8*)&hh[16 + l15][k0];
            bf16x8 e2 = *(const bf16x8*)&hh[32 + l15][k0];
            bf16x8 e3 = *(const bf16x8*)&hh[48 + l15][k0];
            accA[0][0] = __builtin_amdgcn_mfma_f32_16x16x32_bf16(wa0, e0, accA[0][0], 0, 0, 0);
            accA[0][1] = __builtin_amdgcn_mfma_f32_16x16x32_bf16(wa0, e1, accA[0][1], 0, 0, 0);
            accA[0][2] = __builtin_amdgcn_mfma_f32_16x16x32_bf16(wa0, e2, accA[0][2], 0, 0, 0);
            accA[0][3] = __builtin_amdgcn_mfma_f32_16x16x32_bf16(wa0, e3, accA[0][3], 0, 0, 0);
            accA[1][0] = __builtin_amdgcn_mfma_f32_16x16x32_bf16(wa1, e0, accA[1][0], 0, 0, 0);
            accA[1][1] = __builtin_amdgcn_mfma_f32_16x16x32_bf16(wa1, e1, accA[1][1], 0, 0, 0);
            accA[1][2] = __builtin_amdgcn_mfma_f32_16x16x32_bf16(wa1, e2, accA[1][2], 0, 0, 0);
            accA[1][3] = __builtin_amdgcn_mfma_f32_16x16x32_bf16(wa1, e3, accA[1][3], 0, 0, 0);
            accB[0][0] = __builtin_amdgcn_mfma_f32_16x16x32_bf16(wb0, e0, accB[0][0], 0, 0, 0);
            accB[0][1] = __builtin_amdgcn_mfma_f32_16x16x32_bf16(wb0, e1, accB[0][1], 0, 0, 0);
            accB[0][2] = __builtin_amdgcn_mfma_f32_16x16x32_bf16(wb0, e2, accB[0][2], 0, 0, 0);
            accB[0][3] = __builtin_amdgcn_mfma_f32_16x16x32_bf16(wb0, e3, accB[0][3], 0, 0, 0);
            accB[1][0] = __builtin_amdgcn_mfma_f32_16x16x32_bf16(wb1, e0, accB[1][0], 0, 0, 0);
            accB[1][1] = __builtin_amdgcn_mfma_f32_16x16x32_bf16(wb1, e1, accB[1][1], 0, 0, 0);
            accB[1][2] = __builtin_amdgcn_mfma_f32_16x16x32_bf16(wb1, e2, accB[1][2], 0, 0, 0);
            accB[1][3] = __builtin_amdgcn_mfma_f32_16x16x32_bf16(wb1, e3, accB[1][3], 0, 0, 0);
        }

        #pragma unroll
        for (int ct = 0; ct < 2; ++ct) {
            float b1v[4];
            #pragma unroll
            for (int r = 0; r < 4; ++r) b1v[r] = be1[n0 + ct * 16 + q * 4 + r];
            #pragma unroll
            for (int et = 0; et < 4; ++et) {
                int node = nb + et * 16 + l15;
                if (node < N_NODES) {
                    int ch0 = n0 + ct * 16 + q * 4;
                    bf16x4 va, vb;
                    #pragma unroll
                    for (int r = 0; r < 4; ++r) {
                        va[r] = f2bf(accA[ct][et][r] + b1v[r]);
                        vb[r] = f2bf(accB[ct][et][r]);
                    }
                    *(bf16x4*)&Abf[(size_t)node * H + ch0] = va;
                    *(bf16x4*)&Bbf[(size_t)node * H + ch0] = vb;
                }
            }
        }
        return;
    }

    int i = ((int)blockIdx.x - proj_nb) * 256 + tid;
    if (i < nh4) {
        float4 v = ((const float4*)h)[i];
        bf16x4 s4 = { f2bf(v.x), f2bf(v.y), f2bf(v.z), f2bf(v.w) };
        *(bf16x4*)&hbf[i * 4] = s4;
        return;
    }
    i -= nh4;
    if (i < aggz_n) { aggz[i] = uint4{0u, 0u, 0u, 0u}; return; }
    i -= aggz_n;
    if (i < POS4) { pos_dst[i] = pos_src[i]; return; }
    i -= POS4;
    if (erow && i < N_EDGES)
        atomicAdd(&cnt8[(((unsigned)i >> 8) & 7) * CNT_PAD + erow[i]], 1u);
}

// ---- scan8: per-row fold of the 8 XCD sub-histograms; per-bucket bases
// in-place, deg row totals, block-exclusive offs, raw block sums ----
__global__ __launch_bounds__(256) void scan8(unsigned* __restrict__ cnt8,
                                             unsigned* __restrict__ offs,
                                             unsigned* __restrict__ deg,
                                             unsigned* __restrict__ bsum) {
    int t = threadIdx.x;
    int i = blockIdx.x * 256 + t;
    unsigned total = 0;
    if (i < N_NODES) {
        #pragma unroll
        for (int x = 0; x < 8; ++x) {
            unsigned c = cnt8[x * CNT_PAD + i];
            cnt8[x * CNT_PAD + i] = total;   // exclusive per-bucket base
            total += c;
        }
        deg[i] = total;
    }
    unsigned v = total;
    unsigned orig = v;
    #pragma unroll
    for (int d = 1; d < 64; d <<= 1) {
        unsigned n = __shfl_up(v, d);
        if ((t & 63) >= d) v += n;
    }
    __shared__ unsigned wsum[4], woff[4];
    if ((t & 63) == 63) wsum[t >> 6] = v;
    __syncthreads();
    if (t == 0) {
        unsigned r = 0;
        #pragma unroll
        for (int k = 0; k < 4; ++k) { woff[k] = r; r += wsum[k]; }
    }
    __syncthreads();
    unsigned incl = v + woff[t >> 6];
    offs[i] = incl - orig;
    if (t == 255) bsum[blockIdx.x] = incl;       // RAW block total
}

// ---- scatter: scan2 folded in; XCD-local atomic slot grab; PLAIN int2
// store (L2 merges the dense-but-random 8B writes; NT store cost +8us) ----
__global__ __launch_bounds__(256) void scatter_edges(const int* __restrict__ eidx,
        unsigned* __restrict__ cnt8, const unsigned* __restrict__ offs,
        const unsigned* __restrict__ bsum, int2* __restrict__ es) {
    __shared__ unsigned sb[256];
    __shared__ unsigned wsum[4], woff[4];
    int t = threadIdx.x;
    unsigned v = (t < NBS) ? bsum[t] : 0u;
    unsigned orig = v;
    #pragma unroll
    for (int d = 1; d < 64; d <<= 1) {
        unsigned n = __shfl_up(v, d);
        if ((t & 63) >= d) v += n;
    }
    if ((t & 63) == 63) wsum[t >> 6] = v;
    __syncthreads();
    if (t == 0) {
        unsigned r = 0;
        #pragma unroll
        for (int k = 0; k < 4; ++k) { woff[k] = r; r += wsum[k]; }
    }
    __syncthreads();
    sb[t] = v + woff[t >> 6] - orig;
    __syncthreads();
    int e = blockIdx.x * 256 + t;
    if (e < N_EDGES) {
        int r = eidx[e];
        int c = eidx[N_EDGES + e];
        unsigned x = (((unsigned)e >> 8) & 7) * CNT_PAD;   // same bucket as hist
        unsigned p = atomicAdd(&cnt8[x + r], 1u) + offs[r] + sb[r >> 8];
        es[p] = int2{r, c};
    }
}

// ---- edge kernel ----
// PROJ: t = silu(A[row]+B[col]+rn*w256) computed in the gather; accumulate
// T = sum(t) (GEMM2 folded into node kernel). Only GEMM3 (coord head) left.
template<bool AGGBF16, bool SORTED, bool PROJ>
__global__ __launch_bounds__(256, 6) void edge_kernel(
    const short* __restrict__ hbf,
    const short* __restrict__ Abf, const short* __restrict__ Bbf,
    const float* __restrict__ pos,
    const int2* __restrict__ es,
    const int* __restrict__ rsrc, const int* __restrict__ csrc,
    const float* __restrict__ w256f, const float* __restrict__ be1,
    const float* __restrict__ be2, const float* __restrict__ bc1p,
    const float* __restrict__ wc2f, const float* __restrict__ bc2,
    const short* __restrict__ W1b, const short* __restrict__ W2b,
    const short* __restrict__ W3b,
    unsigned* __restrict__ aggb,   // PROJ: T accumulator; else agg(m)
    float* __restrict__ aggf,
    float* __restrict__ pos_out)
{
    __shared__ short s_t[EPB][TSTR];
    __shared__ float s_rn[EPB];
    __shared__ float s_unit[EPB][3];
    __shared__ int   s_row[EPB];
    __shared__ int   s_col[EPB];
    __shared__ float s_dot[EPB];

    const int tid = threadIdx.x;

    int wg;
    {
        const int Q = NWG_EDGE >> 3, R = NWG_EDGE & 7;
        int x = blockIdx.x & 7, k = blockIdx.x >> 3;
        int start = (x < R) ? x * (Q + 1) : R * (Q + 1) + (x - R) * Q;
        wg = start + k;
    }
    const int eb = wg * EPB;

    if (tid < EPB) {
        int ge = eb + tid;
        int r, c;
        if constexpr (SORTED) { int2 rc = es[ge]; r = rc.x; c = rc.y; }
        else { r = rsrc[ge]; c = csrc[ge]; }
        s_row[tid] = r;
        s_col[tid] = c;
        float dx = pos[r*3+0] - pos[c*3+0];
        float dy = pos[r*3+1] - pos[c*3+1];
        float dz = pos[r*3+2] - pos[c*3+2];
        float nrm = sqrtf(dx*dx + dy*dy + dz*dz);
        float rn  = fmaxf(nrm, 1e-8f);
        s_rn[tid] = rn;
        s_unit[tid][0] = dx / rn;
        s_unit[tid][1] = dy / rn;
        s_unit[tid][2] = dz / rn;
        s_dot[tid] = 0.0f;
    }
    __syncthreads();   // b0

    const int lane = tid & 63;
    const int q    = lane >> 4;
    const int l15  = lane & 15;
    const int n0   = (tid >> 6) * 32;
    const int w    = tid >> 6;
    const int rlane = tid & 15;
    const int row0  = tid >> 4;

    if constexpr (PROJ) {
        // fused gather + elementwise -> t
        float4 wv0 = *(const float4*)&w256f[rlane * 8];
        float4 wv1 = *(const float4*)&w256f[rlane * 8 + 4];
        float wv[8] = { wv0.x, wv0.y, wv0.z, wv0.w, wv1.x, wv1.y, wv1.z, wv1.w };
        #pragma unroll
        for (int it = 0; it < 4; ++it) {
            int e = row0 + it * 16;
            bf16x8 a = *(const bf16x8*)&Abf[(size_t)s_row[e] * H + rlane * 8];
            bf16x8 b = *(const bf16x8*)&Bbf[(size_t)s_col[e] * H + rlane * 8];
            float rn = s_rn[e];
            bf16x8 t8;
            #pragma unroll
            for (int j = 0; j < 8; ++j) {
                float x = bf2f(a[j]) + bf2f(b[j]) + rn * wv[j];
                t8[j] = f2bfr(silu(x));
            }
            *(bf16x8*)&s_t[e][rlane * 8] = t8;
        }
        __syncthreads();   // b1: t ready

        // T flush FIRST (fire-and-forget atomics overlap GEMM3's MFMAs)
        {
            const int base = w * 16;
            float a0 = 0.f, a1 = 0.f;
            int cur = s_row[base];
            #pragma unroll
            for (int i = 0; i < 16; ++i) {
                int nd = s_row[base + i];
                if (nd != cur) {
                    unsigned pk = ((unsigned)(unsigned short)f2bfr(a0)) |
                                  (((unsigned)(unsigned short)f2bfr(a1)) << 16);
                    pk_agg_add(&aggb[(size_t)cur * 64 + lane], pk);
                    a0 = 0.f; a1 = 0.f; cur = nd;
                }
                unsigned pr = *(const unsigned*)&s_t[base + i][lane * 2];
                a0 += __builtin_bit_cast(float, pr << 16);
                a1 += __builtin_bit_cast(float, pr & 0xFFFF0000u);
            }
            unsigned pk = ((unsigned)(unsigned short)f2bfr(a0)) |
                          (((unsigned)(unsigned short)f2bfr(a1)) << 16);
            pk_agg_add(&aggb[(size_t)cur * 64 + lane], pk);
        }

        // GEMM3: acc3 = W3@t ; coord dot epilogue
        f32x4 acc3[2][4] = {};
        #pragma unroll
        for (int ks = 0; ks < 4; ++ks) {
            int k0 = ks * 32 + q * 8;
            bf16x8 w30 = *(const bf16x8*)&W3b[(n0 + l15) * 128 + k0];
            bf16x8 w31 = *(const bf16x8*)&W3b[(n0 + 16 + l15) * 128 + k0];
            bf16x8 e0 = *(const bf16x8*)&s_t[l15][k0];
            bf16x8 e1 = *(const bf16x8*)&s_t[16 + l15][k0];
            bf16x8 e2 = *(const bf16x8*)&s_t[32 + l15][k0];
            bf16x8 e3 = *(const bf16x8*)&s_t[48 + l15][k0];
            acc3[0][0] = __builtin_amdgcn_mfma_f32_16x16x32_bf16(w30, e0, acc3[0][0], 0, 0, 0);
            acc3[0][1] = __builtin_amdgcn_mfma_f32_16x16x32_bf16(w30, e1, acc3[0][1], 0, 0, 0);
            acc3[0][2] = __builtin_amdgcn_mfma_f32_16x16x32_bf16(w30, e2, acc3[0][2], 0, 0, 0);
            acc3[0][3] = __builtin_amdgcn_mfma_f32_16x16x32_bf16(w30, e3, acc3[0][3], 0, 0, 0);
            acc3[1][0] = __builtin_amdgcn_mfma_f32_16x16x32_bf16(w31, e0, acc3[1][0], 0, 0, 0);
            acc3[1][1] = __builtin_amdgcn_mfma_f32_16x16x32_bf16(w31, e1, acc3[1][1], 0, 0, 0);
            acc3[1][2] = __builtin_amdgcn_mfma_f32_16x16x32_bf16(w31, e2, acc3[1][2], 0, 0, 0);
            acc3[1][3] = __builtin_amdgcn_mfma_f32_16x16x32_bf16(w31, e3, acc3[1][3], 0, 0, 0);
        }
        {
            float p[4] = {0.f, 0.f, 0.f, 0.f};
            #pragma unroll
            for (int ct = 0; ct < 2; ++ct)
                #pragma unroll
                for (int r = 0; r < 4; ++r) {
                    int ch = n0 + ct * 16 + q * 4 + r;
                    float bias = bc1p[ch];
                    float w2   = wc2f[ch];
                    #pragma unroll
                    for (int et = 0; et < 4; ++et)
                        p[et] += silu(acc3[ct][et][r] + bias) * w2;
                }
            #pragma unroll
            for (int et = 0; et < 4; ++et) {
                float v = p[et];
                v += __shfl_xor(v, 16);
                v += __shfl_xor(v, 32);
                if (q == et) atomicAdd(&s_dot[et * 16 + l15], v);
            }
        }
        __syncthreads();   // b2: s_dot ready
    } else {
        // fallback: stage h|h -> ein, GEMM1 -> t, fused GEMM2+GEMM3 -> m + dot
        __shared__ short s_ein[EPB][264];
        __shared__ short s_m[EPB][136];
        #pragma unroll
        for (int it = 0; it < 8; ++it) {
            int rr = row0 + it * 16;
            int e  = rr & 63, sg = rr >> 6;
            int idx = sg ? s_col[e] : s_row[e];
            bf16x8 v = *(const bf16x8*)&hbf[(size_t)idx * H + rlane * 8];
            *(bf16x8*)&s_ein[e][sg * 128 + rlane * 8] = v;
        }
        __syncthreads();

        f32x4 acc[2][4] = {};
        #pragma unroll
        for (int ks = 0; ks < 8; ++ks) {
            int k0 = ks * 32 + q * 8;
            bf16x8 w0 = *(const bf16x8*)&W1b[(n0 + l15) * 264 + k0];
            bf16x8 w1 = *(const bf16x8*)&W1b[(n0 + 16 + l15) * 264 + k0];
            bf16x8 e0 = *(const bf16x8*)&s_ein[l15][k0];
            bf16x8 e1 = *(const bf16x8*)&s_ein[16 + l15][k0];
            bf16x8 e2 = *(const bf16x8*)&s_ein[32 + l15][k0];
            bf16x8 e3 = *(const bf16x8*)&s_ein[48 + l15][k0];
            acc[0][0] = __builtin_amdgcn_mfma_f32_16x16x32_bf16(w0, e0, acc[0][0], 0, 0, 0);
            acc[0][1] = __builtin_amdgcn_mfma_f32_16x16x32_bf16(w0, e1, acc[0][1], 0, 0, 0);
            acc[0][2] = __builtin_amdgcn_mfma_f32_16x16x32_bf16(w0, e2, acc[0][2], 0, 0, 0);
            acc[0][3] = __builtin_amdgcn_mfma_f32_16x16x32_bf16(w0, e3, acc[0][3], 0, 0, 0);
            acc[1][0] = __builtin_amdgcn_mfma_f32_16x16x32_bf16(w1, e0, acc[1][0], 0, 0, 0);
            acc[1][1] = __builtin_amdgcn_mfma_f32_16x16x32_bf16(w1, e1, acc[1][1], 0, 0, 0);
            acc[1][2] = __builtin_amdgcn_mfma_f32_16x16x32_bf16(w1, e2, acc[1][2], 0, 0, 0);
            acc[1][3] = __builtin_amdgcn_mfma_f32_16x16x32_bf16(w1, e3, acc[1][3], 0, 0, 0);
        }
        {
            float w256v[2][4], b1v[2][4], rn_e[4];
            #pragma unroll
            for (int ct = 0; ct < 2; ++ct)
                #pragma unroll
                for (int r = 0; r < 4; ++r) {
                    int ch = n0 + ct * 16 + q * 4 + r;
                    w256v[ct][r] = w256f[ch];
                    b1v[ct][r]   = be1[ch];
                }
            #pragma unroll
            for (int et = 0; et < 4; ++et) rn_e[et] = s_rn[et * 16 + l15];
            #pragma unroll
            for (int ct = 0; ct < 2; ++ct)
                #pragma unroll
                for (int et = 0; et < 4; ++et) {
                    bf16x4 v;
                    #pragma unroll
                    for (int r = 0; r < 4; ++r)
                        v[r] = f2bfr(silu(acc[ct][et][r] + rn_e[et] * w256v[ct][r] + b1v[ct][r]));
                    *(bf16x4*)&s_t[et * 16 + l15][n0 + ct * 16 + q * 4] = v;
                }
        }
        __syncthreads();   // t ready

        f32x4 acc2[2][4] = {}, acc3[2][4] = {};
        #pragma unroll
        for (int ks = 0; ks < 4; ++ks) {
            int k0 = ks * 32 + q * 8;
            bf16x8 w20 = *(const bf16x8*)&W2b[(n0 + l15) * 128 + k0];
            bf16x8 w21 = *(const bf16x8*)&W2b[(n0 + 16 + l15) * 128 + k0];
            bf16x8 w30 = *(const bf16x8*)&W3b[(n0 + l15) * 128 + k0];
            bf16x8 w31 = *(const bf16x8*)&W3b[(n0 + 16 + l15) * 128 + k0];
            bf16x8 e0 = *(const bf16x8*)&s_t[l15][k0];
            bf16x8 e1 = *(const bf16x8*)&s_t[16 + l15][k0];
            bf16x8 e2 = *(const bf16x8*)&s_t[32 + l15][k0];
            bf16x8 e3 = *(const bf16x8*)&s_t[48 + l15][k0];
            acc2[0][0] = __builtin_amdgcn_mfma_f32_16x16x32_bf16(w20, e0, acc2[0][0], 0, 0, 0);
            acc2[0][1] = __builtin_amdgcn_mfma_f32_16x16x32_bf16(w20, e1, acc2[0][1], 0, 0, 0);
            acc2[0][2] = __builtin_amdgcn_mfma_f32_16x16x32_bf16(w20, e2, acc2[0][2], 0, 0, 0);
            acc2[0][3] = __builtin_amdgcn_mfma_f32_16x16x32_bf16(w20, e3, acc2[0][3], 0, 0, 0);
            acc2[1][0] = __builtin_amdgcn_mfma_f32_16x16x32_bf16(w21, e0, acc2[1][0], 0, 0, 0);
            acc2[1][1] = __builtin_amdgcn_mfma_f32_16x16x32_bf16(w21, e1, acc2[1][1], 0, 0, 0);
            acc2[1][2] = __builtin_amdgcn_mfma_f32_16x16x32_bf16(w21, e2, acc2[1][2], 0, 0, 0);
            acc2[1][3] = __builtin_amdgcn_mfma_f32_16x16x32_bf16(w21, e3, acc2[1][3], 0, 0, 0);
            acc3[0][0] = __builtin_amdgcn_mfma_f32_16x16x32_bf16(w30, e0, acc3[0][0], 0, 0, 0);
            acc3[0][1] = __builtin_amdgcn_mfma_f32_16x16x32_bf16(w30, e1, acc3[0][1], 0, 0, 0);
            acc3[0][2] = __builtin_amdgcn_mfma_f32_16x16x32_bf16(w30, e2, acc3[0][2], 0, 0, 0);
            acc3[0][3] = __builtin_amdgcn_mfma_f32_16x16x32_bf16(w30, e3, acc3[0][3], 0, 0, 0);
            acc3[1][0] = __builtin_amdgcn_mfma_f32_16x16x32_bf16(w31, e0, acc3[1][0], 0, 0, 0);
            acc3[1][1] = __builtin_amdgcn_mfma_f32_16x16x32_bf16(w31, e1, acc3[1][1], 0, 0, 0);
            acc3[1][2] = __builtin_amdgcn_mfma_f32_16x16x32_bf16(w31, e2, acc3[1][2], 0, 0, 0);
            acc3[1][3] = __builtin_amdgcn_mfma_f32_16x16x32_bf16(w31, e3, acc3[1][3], 0, 0, 0);
        }
        {
            float b2v[2][4];
            #pragma unroll
            for (int ct = 0; ct < 2; ++ct)
                #pragma unroll
                for (int r = 0; r < 4; ++r)
                    b2v[ct][r] = be2[n0 + ct * 16 + q * 4 + r];
            #pragma unroll
            for (int ct = 0; ct < 2; ++ct)
                #pragma unroll
                for (int et = 0; et < 4; ++et) {
                    bf16x4 v;
                    #pragma unroll
                    for (int r = 0; r < 4; ++r)
                        v[r] = f2bfr(acc2[ct][et][r] + b2v[ct][r]);
                    *(bf16x4*)&s_m[et * 16 + l15][n0 + ct * 16 + q * 4] = v;
                }
        }
        {
            float p[4] = {0.f, 0.f, 0.f, 0.f};
            #pragma unroll
            for (int ct = 0; ct < 2; ++ct)
                #pragma unroll
                for (int r = 0; r < 4; ++r) {
                    int ch = n0 + ct * 16 + q * 4 + r;
                    float bias = bc1p[ch];
                    float w2   = wc2f[ch];
                    #pragma unroll
                    for (int et = 0; et < 4; ++et)
                        p[et] += silu(acc3[ct][et][r] + bias) * w2;
                }
            #pragma unroll
            for (int et = 0; et < 4; ++et) {
                float v = p[et];
                v += __shfl_xor(v, 16);
                v += __shfl_xor(v, 32);
                if (q == et) atomicAdd(&s_dot[et * 16 + l15], v);
            }
        }
        __syncthreads();   // m + s_dot ready

        if constexpr (AGGBF16) {
            const int base = w * 16;
            float a0 = 0.f, a1 = 0.f;
            int cur = s_row[base];
            #pragma unroll
            for (int i = 0; i < 16; ++i) {
                int nd = s_row[base + i];
                if (nd != cur) {
                    unsigned pk = ((unsigned)(unsigned short)f2bfr(a0)) |
                                  (((unsigned)(unsigned short)f2bfr(a1)) << 16);
                    pk_agg_add(&aggb[(size_t)cur * 64 + lane], pk);
                    a0 = 0.f; a1 = 0.f; cur = nd;
                }
                unsigned pr = *(const unsigned*)&s_m[base + i][lane * 2];
                a0 += __builtin_bit_cast(float, pr << 16);
                a1 += __builtin_bit_cast(float, pr & 0xFFFF0000u);
            }
            unsigned pk = ((unsigned)(unsigned short)f2bfr(a0)) |
                          (((unsigned)(unsigned short)f2bfr(a1)) << 16);
            pk_agg_add(&aggb[(size_t)cur * 64 + lane], pk);
        } else {
            #pragma unroll
            for (int i = 0; i < 16; ++i) {
                int row = w + i * 4;
                unsigned pr = *(const unsigned*)&s_m[row][lane * 2];
                float f0 = __builtin_bit_cast(float, pr << 16);
                float f1 = __builtin_bit_cast(float, pr & 0xFFFF0000u);
                float* dst = &aggf[(size_t)s_row[row] * H + 2 * lane];
                atomicAdd(dst, f0);
                atomicAdd(dst + 1, f1);
            }
        }
    }

    // ---- pos update: scale unit vectors, then run-reduce ----
    if (tid < EPB) {
        float s = tanhf(s_dot[tid] + bc2[0]) * 0.1f;
        s_unit[tid][0] *= s;
        s_unit[tid][1] *= s;
        s_unit[tid][2] *= s;
    }
    __syncthreads();
    if (tid < EPB) {
        int r = s_row[tid];
        bool last = (tid == EPB - 1) || (s_row[tid + 1] != r);
        if (last) {
            float sx = 0.f, sy = 0.f, sz = 0.f;
            for (int j = tid; j >= 0 && s_row[j] == r; --j) {
                sx += s_unit[j][0];
                sy += s_unit[j][1];
                sz += s_unit[j][2];
            }
            atomicAdd(&pos_out[r * 3 + 0], sx);
            atomicAdd(&pos_out[r * 3 + 1], sy);
            atomicAdd(&pos_out[r * 3 + 2], sz);
        }
    }
}

// ---- node kernel: 64 nodes / block. FOLD: input is [h | T], Wn1b's agg
// columns hold Wfold = Wn1[:,128:]@We2, plus per-node deg*bfold bias. ----
template<bool AGGBF16, bool FOLD>
__global__ __launch_bounds__(256) void node_kernel(
    const float* __restrict__ h,
    const unsigned short* __restrict__ aggb, const float* __restrict__ aggf,
    const unsigned* __restrict__ deg, const float* __restrict__ bfold,
    const float* __restrict__ bn1, const float* __restrict__ bn2,
    const short* __restrict__ Wn1b, const short* __restrict__ Wn2b,
    float* __restrict__ hout)
{
    __shared__ short s_a[64][264];
    __shared__ short s_t[64][136];

    const int tid = threadIdx.x;
    const int nb  = blockIdx.x * 64;

    {
        const int rlane = tid & 15;
        const int row0  = tid >> 4;
        #pragma unroll
        for (int it = 0; it < 8; ++it) {
            int rr = row0 + it * 16;
            int e  = rr & 63, sg = rr >> 6;
            int node = nb + e;
            if (node >= N_NODES) node = N_NODES - 1;
            bf16x8 v;
            if (sg == 0) {
                const float4* src = (const float4*)&h[(size_t)node * H + rlane * 8];
                float4 a = src[0], b = src[1];
                v = bf16x8{ f2bf(a.x), f2bf(a.y), f2bf(a.z), f2bf(a.w),
                            f2bf(b.x), f2bf(b.y), f2bf(b.z), f2bf(b.w) };
            } else if constexpr (AGGBF16) {
                v = *(const bf16x8*)&aggb[(size_t)node * H + rlane * 8];
            } else {
                const float* src = &aggf[(size_t)node * H + rlane * 8];
                bf16x8 t;
                #pragma unroll
                for (int j = 0; j < 8; ++j) t[j] = f2bfr(src[j]);
                v = t;
            }
            *(bf16x8*)&s_a[e][sg * 128 + rlane * 8] = v;
        }
    }
    __syncthreads();

    const int lane = tid & 63;
    const int q    = lane >> 4;
    const int l15  = lane & 15;
    const int n0   = (tid >> 6) * 32;

    f32x4 acc[2][4] = {};
    #pragma unroll
    for (int ks = 0; ks < 8; ++ks) {
        int k0 = ks * 32 + q * 8;
        bf16x8 w0 = *(const bf16x8*)&Wn1b[(n0 + l15) * 264 + k0];
        bf16x8 w1 = *(const bf16x8*)&Wn1b[(n0 + 16 + l15) * 264 + k0];
        bf16x8 e0 = *(const bf16x8*)&s_a[l15][k0];
        bf16x8 e1 = *(const bf16x8*)&s_a[16 + l15][k0];
        bf16x8 e2 = *(const bf16x8*)&s_a[32 + l15][k0];
        bf16x8 e3 = *(const bf16x8*)&s_a[48 + l15][k0];
        acc[0][0] = __builtin_amdgcn_mfma_f32_16x16x32_bf16(w0, e0, acc[0][0], 0, 0, 0);
        acc[0][1] = __builtin_amdgcn_mfma_f32_16x16x32_bf16(w0, e1, acc[0][1], 0, 0, 0);
        acc[0][2] = __builtin_amdgcn_mfma_f32_16x16x32_bf16(w0, e2, acc[0][2], 0, 0, 0);
        acc[0][3] = __builtin_amdgcn_mfma_f32_16x16x32_bf16(w0, e3, acc[0][3], 0, 0, 0);
        acc[1][0] = __builtin_amdgcn_mfma_f32_16x16x32_bf16(w1, e0, acc[1][0], 0, 0, 0);
        acc[1][1] = __builtin_amdgcn_mfma_f32_16x16x32_bf16(w1, e1, acc[1][1], 0, 0, 0);
        acc[1][2] = __builtin_amdgcn_mfma_f32_16x16x32_bf16(w1, e2, acc[1][2], 0, 0, 0);
        acc[1][3] = __builtin_amdgcn_mfma_f32_16x16x32_bf16(w1, e3, acc[1][3], 0, 0, 0);
    }
    {
        float b1v[2][4], bf_v[2][4], degf[4];
        #pragma unroll
        for (int ct = 0; ct < 2; ++ct)
            #pragma unroll
            for (int r = 0; r < 4; ++r) {
                int ch = n0 + ct * 16 + q * 4 + r;
                b1v[ct][r] = bn1[ch];
                if constexpr (FOLD) bf_v[ct][r] = bfold[ch];
            }
        if constexpr (FOLD) {
            #pragma unroll
            for (int et = 0; et < 4; ++et) {
                int node = nb + et * 16 + l15;
                if (node >= N_NODES) node = N_NODES - 1;
                degf[et] = (float)deg[node];
            }
        }
        #pragma unroll
        for (int ct = 0; ct < 2; ++ct)
            #pragma unroll
            for (int et = 0; et < 4; ++et) {
                bf16x4 v;
                #pragma unroll
                for (int r = 0; r < 4; ++r) {
                    float x = acc[ct][et][r] + b1v[ct][r];
                    if constexpr (FOLD) x += degf[et] * bf_v[ct][r];
                    v[r] = f2bfr(silu(x));
                }
                *(bf16x4*)&s_t[et * 16 + l15][n0 + ct * 16 + q * 4] = v;
            }
    }
    __syncthreads();

    f32x4 acc2[2][4] = {};
    #pragma unroll
    for (int ks = 0; ks < 4; ++ks) {
        int k0 = ks * 32 + q * 8;
        bf16x8 w0 = *(const bf16x8*)&Wn2b[(n0 + l15) * 128 + k0];
        bf16x8 w1 = *(const bf16x8*)&Wn2b[(n0 + 16 + l15) * 128 + k0];
        bf16x8 e0 = *(const bf16x8*)&s_t[l15][k0];
        bf16x8 e1 = *(const bf16x8*)&s_t[16 + l15][k0];
        bf16x8 e2 = *(const bf16x8*)&s_t[32 + l15][k0];
        bf16x8 e3 = *(const bf16x8*)&s_t[48 + l15][k0];
        acc2[0][0] = __builtin_amdgcn_mfma_f32_16x16x32_bf16(w0, e0, acc2[0][0], 0, 0, 0);
        acc2[0][1] = __builtin_amdgcn_mfma_f32_16x16x32_bf16(w0, e1, acc2[0][1], 0, 0, 0);
        acc2[0][2] = __builtin_amdgcn_mfma_f32_16x16x32_bf16(w0, e2, acc2[0][2], 0, 0, 0);
        acc2[0][3] = __builtin_amdgcn_mfma_f32_16x16x32_bf16(w0, e3, acc2[0][3], 0, 0, 0);
        acc2[1][0] = __builtin_amdgcn_mfma_f32_16x16x32_bf16(w1, e0, acc2[1][0], 0, 0, 0);
        acc2[1][1] = __builtin_amdgcn_mfma_f32_16x16x32_bf16(w1, e1, acc2[1][1], 0, 0, 0);
        acc2[1][2] = __builtin_amdgcn_mfma_f32_16x16x32_bf16(w1, e2, acc2[1][2], 0, 0, 0);
        acc2[1][3] = __builtin_amdgcn_mfma_f32_16x16x32_bf16(w1, e3, acc2[1][3], 0, 0, 0);
    }
    {
        float b2v[2][4];
        #pragma unroll
        for (int ct = 0; ct < 2; ++ct)
            #pragma unroll
            for (int r = 0; r < 4; ++r)
                b2v[ct][r] = bn2[n0 + ct * 16 + q * 4 + r];
        #pragma unroll
        for (int ct = 0; ct < 2; ++ct)
            #pragma unroll
            for (int et = 0; et < 4; ++et) {
                int node = nb + et * 16 + l15;
                if (node < N_NODES) {
                    int ch0 = n0 + ct * 16 + q * 4;
                    const float4 hres = *(const float4*)&h[(size_t)node * H + ch0];
                    float4 o;
                    o.x = acc2[ct][et][0] + b2v[ct][0] + hres.x;
                    o.y = acc2[ct][et][1] + b2v[ct][1] + hres.y;
                    o.z = acc2[ct][et][2] + b2v[ct][2] + hres.z;
                    o.w = acc2[ct][et][3] + b2v[ct][3] + hres.w;
                    *(float4*)&hout[(size_t)node * H + ch0] = o;
                }
            }
    }
}

extern "C" void kernel_launch(void* const* d_in, const int* in_sizes, int n_in,
                              void* d_out, int out_size, void* d_ws, size_t ws_size,
                              hipStream_t stream) {
    const float* h   = (const float*)d_in[0];
    const float* pos = (const float*)d_in[1];
    const int*  eidx = (const int*)d_in[2];
    const float* We1 = (const float*)d_in[3];
    const float* be1 = (const float*)d_in[4];
    const float* We2 = (const float*)d_in[5];
    const float* be2 = (const float*)d_in[6];
    const float* Wn1 = (const float*)d_in[7];
    const float* bn1 = (const float*)d_in[8];
    const float* Wn2 = (const float*)d_in[9];
    const float* bn2 = (const float*)d_in[10];
    const float* Wc1 = (const float*)d_in[11];
    const float* bc1 = (const float*)d_in[12];
    const float* Wc2 = (const float*)d_in[13];
    const float* bc2 = (const float*)d_in[14];

    float* out_h   = (float*)d_out;
    float* out_pos = out_h + (size_t)N_NODES * H;

    char* ws = (char*)d_ws;
    short* W1b  = (short*)(ws);
    short* W2b  = (short*)(ws + 2 * P_W1);
    short* W3b  = (short*)(ws + 2 * (P_W1 + P_W2));
    short* Wn1b = (short*)(ws + 2 * (P_W1 + 2 * P_W2));
    short* Wn2b = (short*)(ws + 2 * (2 * P_W1 + 2 * P_W2));
    float* w256f = (float*)(ws + 2 * (size_t)(2 * P_W1 + 3 * P_W2));
    float* bc1p  = w256f + 128;
    float* bfold = w256f + 256;
    const size_t WSW = 2 * (size_t)(2 * P_W1 + 3 * P_W2) + 2048;
    const size_t HBF = (size_t)N_NODES * H * 2;             // 12.8 MB
    const size_t AGG = (size_t)N_NODES * H * 2;             // 12.8 MB (T or agg)
    const size_t CNT8B = (size_t)8 * CNT_PAD * 4;           // 1.6 MB per-XCD hist
    const size_t OFFB = (size_t)CNT_PAD * 4;
    const size_t DEGB = (size_t)CNT_PAD * 4;
    const size_t BSB  = 256 * 4;
    const size_t ESB  = (size_t)N_EDGES * 8;                // 6.4 MB int2
    const size_t PRJ  = (size_t)N_NODES * H * 2;            // 12.8 MB each
    short* hbf = (short*)(ws + WSW);
    const bool use_bf16 = (ws_size >= WSW + HBF + AGG);
    const bool use_sort = (ws_size >= WSW + HBF + AGG + CNT8B + OFFB + DEGB + BSB + ESB);
    const bool use_proj = (ws_size >= WSW + HBF + AGG + CNT8B + OFFB + DEGB + BSB + ESB + 2 * PRJ);

    const int PW_N = P_TOT + 128 + NW3 + 128 + 128;  // weights+w256+W3+bc1p+bfold

    if (use_bf16) {
        unsigned* aggb = (unsigned*)(ws + WSW + HBF);
        if (use_sort) {
            unsigned* cnt8 = (unsigned*)(ws + WSW + HBF + AGG);
            unsigned* offs = (unsigned*)((char*)cnt8 + CNT8B);
            unsigned* deg  = (unsigned*)((char*)offs + OFFB);
            unsigned* bsum = (unsigned*)((char*)deg + DEGB);
            int2* es = (int2*)((char*)bsum + BSB);
            short* Abf = (short*)((char*)es + ESB);
            short* Bbf = (short*)((char*)Abf + PRJ);

            prep_w<<<(PW_N + 8 * CNT_PAD + 255) / 256, 256, 0, stream>>>(
                We1, We2, Wc1, be2, bc1, Wn1, Wn2,
                W1b, W2b, W3b, Wn1b, Wn2b, w256f, bc1p, bfold,
                cnt8, 8 * CNT_PAD, use_proj ? 1 : 0);
            if (use_proj) {
                const int rest = AGG16 + POS4 + N_EDGES;
                prep2<true><<<PROJ_NB + (rest + 255) / 256, 256, 0, stream>>>(
                    PROJ_NB, h, W1b, be1, Abf, Bbf, 0, nullptr,
                    (uint4*)aggb, AGG16, (float4*)out_pos, (const float4*)pos,
                    eidx, cnt8);
            } else {
                const int rest = NH4 + AGG16 + POS4 + N_EDGES;
                prep2<false><<<(rest + 255) / 256, 256, 0, stream>>>(
                    0, h, nullptr, nullptr, nullptr, nullptr, NH4, hbf,
                    (uint4*)aggb, AGG16, (float4*)out_pos, (const float4*)pos,
                    eidx, cnt8);
            }
            scan8<<<NBS, 256, 0, stream>>>(cnt8, offs, deg, bsum);
            scatter_edges<<<(N_EDGES + 255) / 256, 256, 0, stream>>>(
                eidx, cnt8, offs, bsum, es);
            if (use_proj) {
                edge_kernel<true, true, true><<<NWG_EDGE, 256, 0, stream>>>(
                    hbf, Abf, Bbf, pos, es, nullptr, nullptr,
                    w256f, be1, be2, bc1p, Wc2, bc2,
                    W1b, W2b, W3b, aggb, nullptr, out_pos);
                node_kernel<true, true><<<(N_NODES + 63) / 64, 256, 0, stream>>>(
                    h, (const unsigned short*)aggb, nullptr, deg, bfold,
                    bn1, bn2, Wn1b, Wn2b, out_h);
            } else {
                edge_kernel<true, true, false><<<NWG_EDGE, 256, 0, stream>>>(
                    hbf, nullptr, nullptr, pos, es, nullptr, nullptr,
                    w256f, be1, be2, bc1p, Wc2, bc2,
                    W1b, W2b, W3b, aggb, nullptr, out_pos);
                node_kernel<true, false><<<(N_NODES + 63) / 64, 256, 0, stream>>>(
                    h, (const unsigned short*)aggb, nullptr, nullptr, nullptr,
                    bn1, bn2, Wn1b, Wn2b, out_h);
            }
        } else {
            prep_w<<<(PW_N + 255) / 256, 256, 0, stream>>>(
                We1, We2, Wc1, be2, bc1, Wn1, Wn2,
                W1b, W2b, W3b, Wn1b, Wn2b, w256f, bc1p, bfold,
                nullptr, 0, 0);
            const int rest = NH4 + AGG16 + POS4;
            prep2<false><<<(rest + 255) / 256, 256, 0, stream>>>(
                0, h, nullptr, nullptr, nullptr, nullptr, NH4, hbf,
                (uint4*)aggb, AGG16, (float4*)out_pos, (const float4*)pos,
                nullptr, nullptr);
            edge_kernel<true, false, false><<<NWG_EDGE, 256, 0, stream>>>(
                hbf, nullptr, nullptr, pos, nullptr, eidx, eidx + N_EDGES,
                w256f, be1, be2, bc1p, Wc2, bc2,
                W1b, W2b, W3b, aggb, nullptr, out_pos);
            node_kernel<true, false><<<(N_NODES + 63) / 64, 256, 0, stream>>>(
                h, (const unsigned short*)aggb, nullptr, nullptr, nullptr,
                bn1, bn2, Wn1b, Wn2b, out_h);
        }
    } else {
        // fallback: f32 agg in d_out h region
        prep_w<<<(PW_N + 255) / 256, 256, 0, stream>>>(
            We1, We2, Wc1, be2, bc1, Wn1, Wn2,
            W1b, W2b, W3b, Wn1b, Wn2b, w256f, bc1p, bfold,
            nullptr, 0, 0);
        const int rest = NH4 + POS4;
        prep2<false><<<(rest + 255) / 256, 256, 0, stream>>>(
            0, h, nullptr, nullptr, nullptr, nullptr, NH4, hbf,
            nullptr, 0, (float4*)out_pos, (const float4*)pos,
            nullptr, nullptr);
        hipMemsetAsync(out_h, 0, (size_t)N_NODES * H * sizeof(float), stream);
        edge_kernel<false, false, false><<<NWG_EDGE, 256, 0, stream>>>(
            hbf, nullptr, nullptr, pos, nullptr, eidx, eidx + N_EDGES,
            w256f, be1, be2, bc1p, Wc2, bc2,
            W1b, W2b, W3b, nullptr, out_h, out_pos);
        node_kernel<false, false><<<(N_NODES + 63) / 64, 256, 0, stream>>>(
            h, nullptr, out_h, nullptr, nullptr, bn1, bn2, Wn1b, Wn2b, out_h);
    }
}